// Round 5
// baseline (1812.488 us; speedup 1.0000x reference)
//
#include <hip/hip_runtime.h>
#include <stdint.h>

#define DEV static __device__ __forceinline__

using short8 = __attribute__((ext_vector_type(8))) short;
using f32x4  = __attribute__((ext_vector_type(4))) float;
using gbl_u32 = const __attribute__((address_space(1))) unsigned int;
using lds_u32 = __attribute__((address_space(3))) unsigned int;

DEV float bf2f(short s) {
  unsigned u = ((unsigned)(unsigned short)s) << 16;
  float f; __builtin_memcpy(&f, &u, 4); return f;
}
DEV short f2bf(float f) {
  unsigned u; __builtin_memcpy(&u, &f, 4);
  u = (u + 0x7fffu + ((u >> 16) & 1u)) >> 16;
  return (short)u;
}
DEV void gload_lds16(const void* g, void* l) {
  __builtin_amdgcn_global_load_lds((gbl_u32*)g, (lds_u32*)l, 16, 0, 0);
}
DEV float sigm(float x) { return 1.f / (1.f + __expf(-x)); }
DEV float tanh_f(float x) {
  float e = __expf(2.f * x);
  return 1.f - 2.f * __builtin_amdgcn_rcpf(e + 1.f);
}

// ------------------------------------------------------------------
// pack kernels
// ------------------------------------------------------------------
__global__ void pack_cov_k(const float* __restrict__ past, const float* __restrict__ fut,
                           short* __restrict__ covp) {
  const int n = 192 * 256 * 64;
  for (int i = blockIdx.x * blockDim.x + threadIdx.x; i < n; i += gridDim.x * blockDim.x) {
    int c = i & 63, r = i >> 6;
    int b = r & 255, t = r >> 8;
    float v = (t < 128) ? past[((size_t)b * 128 + t) * 64 + c]
                        : fut[((size_t)b * 64 + (t - 128)) * 64 + c];
    covp[i] = f2bf(v);
  }
}

__global__ void pack_lab_k(const float* __restrict__ lab, short* __restrict__ labp) {
  const int n = 128 * 256 * 32;
  for (int i = blockIdx.x * blockDim.x + threadIdx.x; i < n; i += gridDim.x * blockDim.x) {
    int c = i & 31, r = i >> 5;
    int b = r & 255, t = r >> 8;
    labp[i] = f2bf(lab[((size_t)b * 128 + t) * 32 + c]);
  }
}

DEV int gru_srcrow(int pr) {
  int j = pr / 96, w = pr % 96;
  return ((w >> 5) << 9) + j * 32 + (w & 31);
}

// Whh -> fragment image: [j(16)][kqg(16)*6+tile][lane(64)][8 elems]
__global__ void pack_gru_k(const float* __restrict__ Wih, const float* __restrict__ Whh,
                           const float* __restrict__ bih, const float* __restrict__ bhh,
                           int Kin, short* __restrict__ Wihp, short* __restrict__ Whhp,
                           float* __restrict__ bihp, float* __restrict__ bhhp) {
  const int nW1 = 1536 * Kin, nW2 = 1536 * 512;
  const int total = nW1 + nW2 + 3072;
  for (int idx = blockIdx.x * blockDim.x + threadIdx.x; idx < total; idx += gridDim.x * blockDim.x) {
    if (idx < nW1) {
      int pr = idx / Kin, k = idx - pr * Kin;
      Wihp[idx] = f2bf(Wih[(size_t)gru_srcrow(pr) * Kin + k]);
    } else if (idx < nW1 + nW2) {
      int ii = idx - nW1;
      int j = ii / 49152, r = ii - j * 49152;
      int i = r & 7, slot = r >> 3;
      int l = slot & 63, sf = slot >> 6;
      int kqg = sf / 6, tile = sf - kqg * 6;
      int w = tile * 16 + (l & 15);
      int k = kqg * 32 + (l >> 4) * 8 + i;
      int srow = (w >> 5) * 512 + j * 32 + (w & 31);
      Whhp[ii] = f2bf(Whh[(size_t)srow * 512 + k]);
    } else if (idx < nW1 + nW2 + 1536) {
      int pr = idx - nW1 - nW2;
      bihp[pr] = bih[gru_srcrow(pr)];
    } else {
      int pr = idx - nW1 - nW2 - 1536;
      bhhp[pr] = bhh[gru_srcrow(pr)];
    }
  }
}

__global__ void pack_misc_k(const float* __restrict__ fw, const float* __restrict__ w1,
                            const float* __restrict__ w2, short* __restrict__ fwb,
                            short* __restrict__ w1b, short* __restrict__ w2b) {
  const int n1 = 64 * 512, n2 = 128 * 32, n3 = 128 * 128;
  const int total = n1 + n2 + n3;
  for (int i = blockIdx.x * blockDim.x + threadIdx.x; i < total; i += gridDim.x * blockDim.x) {
    if (i < n1) fwb[i] = f2bf(fw[i]);
    else if (i < n1 + n2) w1b[i - n1] = f2bf(w1[i - n1]);
    else w2b[i - n1 - n2] = f2bf(w2[i - n1 - n2]);
  }
}

// vae weight frag images: 52 frags x [lane(64)][8] bf16.
// [0,4): outW kt*2+nt  [4,12): cmuW kt*4+nt  [12,20): W1 nt  [20,52): W2 kt*8+nt
__global__ void pack_vae_k(const float* __restrict__ outW, const float* __restrict__ cmuW,
                           const float* __restrict__ W1, const float* __restrict__ W2,
                           short* __restrict__ vwf) {
  const int n = 52 * 512;
  for (int i = blockIdx.x * blockDim.x + threadIdx.x; i < n; i += gridDim.x * blockDim.x) {
    int fr = i >> 9, l = (i >> 3) & 63, e = i & 7;
    int lm = l & 15, lh = l >> 4;
    float v;
    if (fr < 4) { int kt = fr >> 1, nt = fr & 1; v = outW[(nt * 16 + lm) * 64 + kt * 32 + lh * 8 + e]; }
    else if (fr < 12) { int f = fr - 4, kt = f >> 2, nt = f & 3; v = cmuW[(nt * 16 + lm) * 64 + kt * 32 + lh * 8 + e]; }
    else if (fr < 20) { int nt = fr - 12; v = W1[(nt * 16 + lm) * 32 + lh * 8 + e]; }
    else { int f = fr - 20, kt = f >> 3, nt = f & 7; v = W2[(nt * 16 + lm) * 128 + kt * 32 + lh * 8 + e]; }
    vwf[i] = f2bf(v);
  }
}

// ------------------------------------------------------------------
// GEMM: C[M][N] = act(A @ B^T + bias). AFRAG: A in hbuf fragment image.
// CMODE 0: row-major out. CMODE 1: C-frag f32 image [rowblk16][coltile16][lane][4].
// ------------------------------------------------------------------
template <int BK, bool OBF16, bool DOTANH, bool AFRAG, int CMODE = 0>
__global__ __launch_bounds__(256) void gemm_bt_k(
    const short* __restrict__ A, const short* __restrict__ Bw,
    const float* __restrict__ bias, void* __restrict__ Cout,
    int M, int N, int K) {
  constexpr int BM = 128, BN = 128;
  __shared__ short As[BM * BK];
  __shared__ short Bs[BN * BK];
  const int tid = threadIdx.x, lane = tid & 63;
  const int wave = tid >> 6, wm = wave >> 1, wn = wave & 1;
  const int bm = blockIdx.x, bn = blockIdx.y;
  const int lm = lane & 15, lk = (lane >> 4) * 8;
  f32x4 acc[4][4] = {};
  for (int k0 = 0; k0 < K; k0 += BK) {
    constexpr int BYTES = BM * BK * 2;
#pragma unroll
    for (int it = 0; it < BYTES / 4096; ++it) {
      int o = it * 4096 + tid * 16;
      if (AFRAG) {
        int sub = o >> 10, gl = sub >> 1, kk2 = sub & 1, inb = o & 1023;
        size_t region = ((size_t)(bm >> 1) * 16 + (bm & 1) * 8 + gl) * 16 + (k0 >> 5) + kk2;
        gload_lds16((const char*)A + region * 1024 + inb, (char*)As + (o - lane * 16));
      } else {
        int row = o / (BK * 2);
        int col = o - row * (BK * 2);
        const char* srcA = (const char*)A + (((size_t)(bm * BM + row)) * K + k0) * 2 + col;
        gload_lds16(srcA, (char*)As + (o - lane * 16));
      }
      int row = o / (BK * 2);
      int col = o - row * (BK * 2);
      int rb = bn * BN + row;
      if (rb >= N) rb = N - 1;
      const char* srcB = (const char*)Bw + (((size_t)rb) * K + k0) * 2 + col;
      gload_lds16(srcB, (char*)Bs + (o - lane * 16));
    }
    __syncthreads();
#pragma unroll
    for (int kk = 0; kk < BK / 32; ++kk) {
      short8 av[4], bv[4];
#pragma unroll
      for (int i = 0; i < 4; ++i) {
        if (AFRAG)
          av[i] = *(const short8*)((const char*)As + (((wm * 4 + i) * 2 + kk) << 10) + lane * 16);
        else
          av[i] = *(const short8*)((const char*)As + ((wm * 64 + i * 16 + lm) * BK + kk * 32 + lk) * 2);
      }
#pragma unroll
      for (int jv = 0; jv < 4; ++jv)
        bv[jv] = *(const short8*)((const char*)Bs + ((wn * 64 + jv * 16 + lm) * BK + kk * 32 + lk) * 2);
#pragma unroll
      for (int i = 0; i < 4; ++i)
#pragma unroll
        for (int jv = 0; jv < 4; ++jv)
          acc[i][jv] = __builtin_amdgcn_mfma_f32_16x16x32_bf16(av[i], bv[jv], acc[i][jv], 0, 0, 0);
    }
    __syncthreads();
  }
  if (CMODE == 1) {
    const int NT = N >> 4;
#pragma unroll
    for (int jv = 0; jv < 4; ++jv) {
      int col = bn * BN + wn * 64 + jv * 16 + lm;
      if (col >= N) continue;
      float bvl = bias[col];
#pragma unroll
      for (int i = 0; i < 4; ++i) {
        int rowblk = bm * 8 + wm * 4 + i;
        f32x4 v = acc[i][jv];
        v[0] += bvl; v[1] += bvl; v[2] += bvl; v[3] += bvl;
        *(f32x4*)((float*)Cout + (((size_t)rowblk * NT + (col >> 4)) << 8) + lane * 4) = v;
      }
    }
  } else {
#pragma unroll
    for (int jv = 0; jv < 4; ++jv) {
      int col = bn * BN + wn * 64 + jv * 16 + lm;
      if (col >= N) continue;
      float bvl = bias[col];
#pragma unroll
      for (int i = 0; i < 4; ++i) {
        int row0 = bm * BM + wm * 64 + i * 16 + (lane >> 4) * 4;
#pragma unroll
        for (int r = 0; r < 4; ++r) {
          float v = acc[i][jv][r] + bvl;
          if (DOTANH) v = tanhf(v);
          size_t off = (size_t)(row0 + r) * N + col;
          if (OBF16) ((short*)Cout)[off] = f2bf(v);
          else ((float*)Cout)[off] = v;
        }
      }
    }
  }
}

// ------------------------------------------------------------------
// GRU scan (unchanged from R4, passing): 16 groups x 16 hidden-blocks,
// relaxed agent atomics for h + padded per-dispatch counters/flags.
// ------------------------------------------------------------------
template <int SCHEME>
__global__ __launch_bounds__(256) void gru_scan_k(
    const short* __restrict__ xg, const short* __restrict__ Whhp,
    const float* __restrict__ bhhp, short* __restrict__ hbuf,
    unsigned int* __restrict__ ctr, unsigned int* __restrict__ flags, int t0) {
  __shared__ short Wl[96 * 512];
  __shared__ short hs[16 * 512];
  __shared__ float sc[2][16 * 101];
  __shared__ float bhs[96];
  const int tid = threadIdx.x, lane = tid & 63, wave = tid >> 6;
  const int x = blockIdx.x;
  const int g = (x & 7) + ((x >> 7) << 3);
  const int j = (x >> 3) & 15;
  unsigned int* __restrict__ myctr = ctr + g * 64;
  unsigned int* __restrict__ myflags = flags + g * 16;
  unsigned int* __restrict__ hbuf32 = (unsigned int*)hbuf;
  {
    const char* wsrc = (const char*)Whhp + (size_t)j * 98304;
#pragma unroll 4
    for (int it = 0; it < 24; ++it) {
      int o = it * 4096 + tid * 16;
      gload_lds16(wsrc + o, (char*)Wl + (o - lane * 16));
    }
    if (tid < 96) bhs[tid] = bhhp[j * 96 + tid];
  }
  const int wk = wave >> 1, wn3 = wave & 1;
  const int m = tid >> 4, up = tid & 15, u0 = up * 2;
  for (int tl = 0; tl < 48; ++tl) {
    const int t = t0 + tl;
    const char* hsrc = (const char*)hbuf + ((size_t)t * 16 + g) * 16384;
#pragma unroll
    for (int it = 0; it < 4; ++it) {
      int o = it * 4096 + tid * 16;
      gload_lds16(hsrc + o, (char*)hs + (o - lane * 16));
    }
    const unsigned int* xp = (const unsigned int*)(xg + ((size_t)tl * 256 + g * 16 + m) * 1536 + j * 96);
    unsigned int xr2 = xp[up], xz2 = xp[16 + up], xn2 = xp[32 + up];
    __syncthreads();
    f32x4 a3[3] = {};
#pragma unroll
    for (int kq = 0; kq < 8; ++kq) {
      int kqg = wk * 8 + kq;
      short8 av = *(const short8*)((const char*)hs + (kqg << 10) + lane * 16);
#pragma unroll
      for (int n = 0; n < 3; ++n) {
        short8 bv = *(const short8*)((const char*)Wl + ((kqg * 6 + wn3 * 3 + n) << 10) + lane * 16);
        a3[n] = __builtin_amdgcn_mfma_f32_16x16x32_bf16(av, bv, a3[n], 0, 0, 0);
      }
    }
#pragma unroll
    for (int n = 0; n < 3; ++n)
#pragma unroll
      for (int rr = 0; rr < 4; ++rr)
        sc[wk][((lane >> 4) * 4 + rr) * 101 + (wn3 * 3 + n) * 16 + (lane & 15)] = a3[n][rr];
    __syncthreads();
    {
      float Sr0 = sc[0][m * 101 + u0] + sc[1][m * 101 + u0];
      float Sr1 = sc[0][m * 101 + u0 + 1] + sc[1][m * 101 + u0 + 1];
      float Sz0 = sc[0][m * 101 + 32 + u0] + sc[1][m * 101 + 32 + u0];
      float Sz1 = sc[0][m * 101 + 33 + u0] + sc[1][m * 101 + 33 + u0];
      float Sn0 = sc[0][m * 101 + 64 + u0] + sc[1][m * 101 + 64 + u0];
      float Sn1 = sc[0][m * 101 + 65 + u0] + sc[1][m * 101 + 65 + u0];
      int hpa = ((j * 64 + (up >> 2) * 16 + m) << 4) + ((u0 & 7) << 1);
      unsigned int hpu = *(const unsigned int*)((const char*)hs + hpa);
      float hp0 = bf2f((short)(hpu & 0xffff)), hp1 = bf2f((short)(hpu >> 16));
      float r0 = sigm(bf2f((short)(xr2 & 0xffff)) + Sr0 + bhs[u0]);
      float r1 = sigm(bf2f((short)(xr2 >> 16)) + Sr1 + bhs[u0 + 1]);
      float z0 = sigm(bf2f((short)(xz2 & 0xffff)) + Sz0 + bhs[32 + u0]);
      float z1 = sigm(bf2f((short)(xz2 >> 16)) + Sz1 + bhs[33 + u0]);
      float n0 = tanhf(bf2f((short)(xn2 & 0xffff)) + r0 * (Sn0 + bhs[64 + u0]));
      float n1 = tanhf(bf2f((short)(xn2 >> 16)) + r1 * (Sn1 + bhs[65 + u0]));
      float h0 = (1.f - z0) * n0 + z0 * hp0;
      float h1 = (1.f - z1) * n1 + z1 * hp1;
      unsigned int hv = (unsigned int)(unsigned short)f2bf(h0) |
                        ((unsigned int)(unsigned short)f2bf(h1) << 16);
      size_t oi = ((size_t)(t + 1) * 16 + g) * 4096 +
                  (j * 64 + (up >> 2) * 16 + m) * 4 + (up & 3);
      __hip_atomic_store(hbuf32 + oi, hv, __ATOMIC_RELAXED, __HIP_MEMORY_SCOPE_AGENT);
    }
    __syncthreads();
    if constexpr (SCHEME == 1) {
      if (tid == 0) {
        __hip_atomic_fetch_add(myctr, 1u, __ATOMIC_RELAXED, __HIP_MEMORY_SCOPE_AGENT);
        const unsigned tgt = 16u * (unsigned)(tl + 1);
        int guard = 0;
        while (__hip_atomic_load(myctr, __ATOMIC_RELAXED, __HIP_MEMORY_SCOPE_AGENT) < tgt &&
               ++guard < 200000) {}
      }
    } else {
      const unsigned tgt = (unsigned)(tl + 1);
      if (tid == 0)
        __hip_atomic_store(myflags + j, tgt, __ATOMIC_RELAXED, __HIP_MEMORY_SCOPE_AGENT);
      if (tid < 16) {
        int guard = 0;
        while (__hip_atomic_load(myflags + tid, __ATOMIC_RELAXED, __HIP_MEMORY_SCOPE_AGENT) < tgt &&
               ++guard < 200000) {}
      }
    }
    __syncthreads();
  }
}

// ------------------------------------------------------------------
// VAE scan: 16 single-wave blocks x 16 batches. State in MFMA C-space
// (lane: col c=l&15, rows m4*4+r). All matvecs via 16x16x32 bf16 MFMA;
// C->A transposes via XOR-swizzled LDS. feat/ctrl read from C-frag images.
// ------------------------------------------------------------------
__global__ __launch_bounds__(64) void vae_k(
    const float* __restrict__ feat_img,   // [3072][4][64][4] f32
    const float* __restrict__ ctrl_img,   // [2048][8][64][4] f32
    const short* __restrict__ vwf,        // 52 frag images
    const float* __restrict__ flow_u, const float* __restrict__ flow_w,
    const float* __restrict__ flow_b, const float* __restrict__ outb,
    const float* __restrict__ b1, const float* __restrict__ b2,
    const float* __restrict__ cmub, float* __restrict__ out) {
  __shared__ short Wctl[40 * 512];  // W1 frags [0,8), W2 frags [8,40)
  __shared__ short muA[16 * 64];
  __shared__ short predA[16 * 32];
  __shared__ short hdnA[16 * 128];
  const int l = threadIdx.x, m4 = l >> 4, c = l & 15, bg = blockIdx.x;
  {
    const char* src = (const char*)vwf + 12288;
#pragma unroll 8
    for (int it = 0; it < 40; ++it) {
      int o = it * 1024 + l * 16;
      gload_lds16(src + o, (char*)Wctl + (o - l * 16));
    }
  }
  short8 outWf[2][2], cmuf[2][4];
#pragma unroll
  for (int kt = 0; kt < 2; ++kt)
#pragma unroll
    for (int nt = 0; nt < 2; ++nt)
      outWf[kt][nt] = *(const short8*)(vwf + (kt * 2 + nt) * 512 + l * 8);
#pragma unroll
  for (int kt = 0; kt < 2; ++kt)
#pragma unroll
    for (int nt = 0; nt < 4; ++nt)
      cmuf[kt][nt] = *(const short8*)(vwf + (4 + kt * 4 + nt) * 512 + l * 8);
  float fw4[4], fu4[4], fb4[4], cmub4[4], outb2[2], b1_8[8], b2_8[8];
#pragma unroll
  for (int jt = 0; jt < 4; ++jt) {
    fw4[jt] = flow_w[jt * 16 + c]; fu4[jt] = flow_u[jt * 16 + c];
    fb4[jt] = flow_b[jt * 16 + c]; cmub4[jt] = cmub[jt * 16 + c];
  }
  outb2[0] = outb[c]; outb2[1] = outb[16 + c];
#pragma unroll
  for (int nt = 0; nt < 8; ++nt) { b1_8[nt] = b1[nt * 16 + c]; b2_8[nt] = b2[nt * 16 + c]; }
  f32x4 muC[4], varC[4], fN[4];
#pragma unroll
  for (int jt = 0; jt < 4; ++jt) {
    muC[jt] = f32x4{0.f, 0.f, 0.f, 0.f};
    varC[jt] = f32x4{1.f, 1.f, 1.f, 1.f};
    fN[jt] = *(const f32x4*)(feat_img + ((size_t)bg * 4 + jt) * 256 + l * 4);
  }
  __syncthreads();
  for (int t = 0; t < 192; ++t) {
    // ---- flow (elementwise, C-space); uses prefetched fN ----
    f32x4 muPr[4], varPr[4];
#pragma unroll
    for (int jt = 0; jt < 4; ++jt)
#pragma unroll
      for (int r = 0; r < 4; ++r) {
        float m = muC[jt][r];
        float a = tanh_f(fw4[jt] * m + fb4[jt]);
        muPr[jt][r] = fu4[jt] * a + fN[jt][r] + m;
        float coef = fu4[jt] * fw4[jt] * (1.f - a * a);
        varPr[jt][r] = 2.f * coef * varC[jt][r] + varC[jt][r] + 1.f;
      }
    // prefetch feat for t+1
    if (t + 1 < 192) {
#pragma unroll
      for (int jt = 0; jt < 4; ++jt)
        fN[jt] = *(const f32x4*)(feat_img + (((size_t)(t + 1) * 16 + bg) * 4 + jt) * 256 + l * 4);
    }
    // ctrl loads for this step (consumed late)
    f32x4 cld[8];
    if (t < 128) {
#pragma unroll
      for (int q = 0; q < 8; ++q)
        cld[q] = *(const f32x4*)(ctrl_img + (((size_t)t * 16 + bg) * 8 + q) * 256 + l * 4);
    }
    // ---- T1: mu_pr C -> A (bf16, swizzled) ----
#pragma unroll
    for (int jt = 0; jt < 4; ++jt)
#pragma unroll
      for (int r = 0; r < 4; ++r) {
        int row = m4 * 4 + r;
        *(short*)((char*)muA + ((row * 128 + (jt * 16 + c) * 2) ^ ((row & 7) << 4))) = f2bf(muPr[jt][r]);
      }
    __syncthreads();
    short8 muAf[2];
#pragma unroll
    for (int kt = 0; kt < 2; ++kt)
      muAf[kt] = *(const short8*)((const char*)muA + ((c * 128 + kt * 64 + m4 * 16) ^ ((c & 7) << 4)));
    // ---- pred = mu_pr @ outW^T + outb ----
    f32x4 predC[2] = {f32x4{0.f, 0.f, 0.f, 0.f}, f32x4{0.f, 0.f, 0.f, 0.f}};
#pragma unroll
    for (int nt = 0; nt < 2; ++nt) {
#pragma unroll
      for (int kt = 0; kt < 2; ++kt)
        predC[nt] = __builtin_amdgcn_mfma_f32_16x16x32_bf16(muAf[kt], outWf[kt][nt], predC[nt], 0, 0, 0);
#pragma unroll
      for (int r = 0; r < 4; ++r) predC[nt][r] += outb2[nt];
    }
#pragma unroll
    for (int nt = 0; nt < 2; ++nt)
#pragma unroll
      for (int r = 0; r < 4; ++r)
        out[(size_t)(bg * 16 + m4 * 4 + r) * 6144 + t * 32 + nt * 16 + c] = predC[nt][r];
    // ---- mc = mu_pr @ cmuW^T ----
    f32x4 mcC[4] = {f32x4{0.f,0.f,0.f,0.f}, f32x4{0.f,0.f,0.f,0.f},
                    f32x4{0.f,0.f,0.f,0.f}, f32x4{0.f,0.f,0.f,0.f}};
#pragma unroll
    for (int nt = 0; nt < 4; ++nt)
#pragma unroll
      for (int kt = 0; kt < 2; ++kt)
        mcC[nt] = __builtin_amdgcn_mfma_f32_16x16x32_bf16(muAf[kt], cmuf[kt][nt], mcC[nt], 0, 0, 0);
    // ---- control: cm raw + cls raw ----
    f32x4 cmC[4], csR[4];
    if (t < 128) {
#pragma unroll
      for (int jt = 0; jt < 4; ++jt) { cmC[jt] = cld[jt]; csR[jt] = cld[4 + jt]; }
    } else {
      // T2: pred C -> A
#pragma unroll
      for (int nt = 0; nt < 2; ++nt)
#pragma unroll
        for (int r = 0; r < 4; ++r) {
          int row = m4 * 4 + r;
          *(short*)((char*)predA + ((row * 64 + (nt * 16 + c) * 2) ^ ((row & 3) << 4))) = f2bf(predC[nt][r]);
        }
      __syncthreads();
      short8 pAf = *(const short8*)((const char*)predA + ((c * 64 + m4 * 16) ^ ((c & 3) << 4)));
      f32x4 hdnC[8];
#pragma unroll
      for (int nt = 0; nt < 8; ++nt) {
        short8 w1f = *(const short8*)((const char*)Wctl + nt * 1024 + l * 16);
        f32x4 z = {0.f, 0.f, 0.f, 0.f};
        z = __builtin_amdgcn_mfma_f32_16x16x32_bf16(pAf, w1f, z, 0, 0, 0);
#pragma unroll
        for (int r = 0; r < 4; ++r) hdnC[nt][r] = tanh_f(z[r] + b1_8[nt]);
      }
      // T3: hdn C -> A
#pragma unroll
      for (int nt = 0; nt < 8; ++nt)
#pragma unroll
        for (int r = 0; r < 4; ++r) {
          int row = m4 * 4 + r;
          *(short*)((char*)hdnA + ((row * 256 + (nt * 16 + c) * 2) ^ ((row & 7) << 4))) = f2bf(hdnC[nt][r]);
        }
      __syncthreads();
      short8 hAf[4];
#pragma unroll
      for (int kc = 0; kc < 4; ++kc)
        hAf[kc] = *(const short8*)((const char*)hdnA + ((c * 256 + kc * 64 + m4 * 16) ^ ((c & 7) << 4)));
#pragma unroll
      for (int nt = 0; nt < 8; ++nt) {
        f32x4 z = {0.f, 0.f, 0.f, 0.f};
#pragma unroll
        for (int kc = 0; kc < 4; ++kc) {
          short8 w2f = *(const short8*)((const char*)Wctl + (8 + kc * 8 + nt) * 1024 + l * 16);
          z = __builtin_amdgcn_mfma_f32_16x16x32_bf16(hAf[kc], w2f, z, 0, 0, 0);
        }
#pragma unroll
        for (int r = 0; r < 4; ++r) {
          float v = z[r] + b2_8[nt];
          if (nt < 4) cmC[nt][r] = v;
          else csR[nt - 4][r] = v;
        }
      }
    }
    // ---- finalize cm/cs, store, fuse ----
#pragma unroll
    for (int jt = 0; jt < 4; ++jt)
#pragma unroll
      for (int r = 0; r < 4; ++r) {
        float vp = varPr[jt][r], mp = muPr[jt][r];
        float cmv = cmC[jt][r] - (mcC[jt][r] + cmub4[jt]);
        float x = csR[jt][r];
        float cs = (x > 20.f) ? x : __logf(1.f + __expf(x));
        if (t >= 1) {
          size_t b = (size_t)(bg * 16 + m4 * 4 + r);
          out[1572864 + b * 12224 + (size_t)(t - 1) * 64 + jt * 16 + c] = cmv;
          out[4702208 + b * 12224 + (size_t)(t - 1) * 64 + jt * 16 + c] = cs;
        }
        float s = cs + vp;
        float rs = __builtin_amdgcn_rcpf(s);
        muC[jt][r] = cs * rs * mp + vp * rs * cmv;
        varC[jt][r] = vp * cs * rs;
      }
  }
}

// ------------------------------------------------------------------
extern "C" void kernel_launch(void* const* d_in, const int* in_sizes, int n_in,
                              void* d_out, int out_size, void* d_ws, size_t ws_size,
                              hipStream_t stream) {
  (void)in_sizes; (void)n_in; (void)out_size; (void)ws_size;
  const float* past_input = (const float*)d_in[0];
  const float* past_label = (const float*)d_in[1];
  const float* future_input = (const float*)d_in[2];
  const float* Wih0 = (const float*)d_in[3];
  const float* Whh0 = (const float*)d_in[4];
  const float* bih0 = (const float*)d_in[5];
  const float* bhh0 = (const float*)d_in[6];
  const float* Wih1 = (const float*)d_in[7];
  const float* Whh1 = (const float*)d_in[8];
  const float* bih1 = (const float*)d_in[9];
  const float* bhh1 = (const float*)d_in[10];
  const float* flow_u = (const float*)d_in[11];
  const float* flow_w = (const float*)d_in[12];
  const float* flow_b = (const float*)d_in[13];
  const float* feat_W = (const float*)d_in[14];
  const float* feat_b = (const float*)d_in[15];
  const float* ctrl_W1 = (const float*)d_in[16];
  const float* ctrl_b1 = (const float*)d_in[17];
  const float* ctrl_W2 = (const float*)d_in[18];
  const float* ctrl_b2 = (const float*)d_in[19];
  const float* cmuW = (const float*)d_in[20];
  const float* cmub = (const float*)d_in[21];
  const float* outW = (const float*)d_in[22];
  const float* outb = (const float*)d_in[23];

  char* ws = (char*)d_ws;
  size_t off = 0;
  auto alloc = [&](size_t bytes) -> char* {
    char* p = ws + off;
    off += (bytes + 255) & ~(size_t)255;
    return p;
  };
  short* covp  = (short*)alloc(49152ull * 64 * 2);
  short* labp  = (short*)alloc(32768ull * 32 * 2);
  short* Wih0p = (short*)alloc(1536ull * 64 * 2);
  short* Whh0p = (short*)alloc(1536ull * 512 * 2);
  short* Wih1p = (short*)alloc(1536ull * 512 * 2);
  short* Whh1p = (short*)alloc(1536ull * 512 * 2);
  float* bih0p = (float*)alloc(1536 * 4);
  float* bhh0p = (float*)alloc(1536 * 4);
  float* bih1p = (float*)alloc(1536 * 4);
  float* bhh1p = (float*)alloc(1536 * 4);
  short* featWb = (short*)alloc(64ull * 512 * 2);
  short* W1b   = (short*)alloc(128ull * 32 * 2);
  short* W2b   = (short*)alloc(128ull * 128 * 2);
  short* vwf   = (short*)alloc(52ull * 512 * 2);
  short* xgc   = (short*)alloc(48ull * 256 * 1536 * 2);
  short* h1buf = (short*)alloc(193ull * 256 * 512 * 2);
  short* cfbuf = (short*)alloc(193ull * 256 * 512 * 2);
  unsigned int* ctr = (unsigned int*)alloc(8 * 16 * 64 * 4);
  unsigned int* flg = (unsigned int*)alloc(8 * 16 * 16 * 4);
  float* feat_img = (float*)xgc;                           // overlays after scans
  short* hdnb     = (short*)((char*)xgc + 12582912);
  float* ctrl_img = (float*)((char*)xgc + 20971520);

  hipMemsetAsync(ctr, 0, 8 * 16 * 64 * 4, stream);
  hipMemsetAsync(flg, 0, 8 * 16 * 16 * 4, stream);
  hipMemsetAsync(h1buf, 0, 256 * 512 * 2, stream);
  hipMemsetAsync(cfbuf, 0, 256 * 512 * 2, stream);

  pack_cov_k<<<2048, 256, 0, stream>>>(past_input, future_input, covp);
  pack_lab_k<<<1024, 256, 0, stream>>>(past_label, labp);
  pack_gru_k<<<1024, 256, 0, stream>>>(Wih0, Whh0, bih0, bhh0, 64, Wih0p, Whh0p, bih0p, bhh0p);
  pack_gru_k<<<1024, 256, 0, stream>>>(Wih1, Whh1, bih1, bhh1, 512, Wih1p, Whh1p, bih1p, bhh1p);
  pack_misc_k<<<64, 256, 0, stream>>>(feat_W, ctrl_W1, ctrl_W2, featWb, W1b, W2b);
  pack_vae_k<<<104, 256, 0, stream>>>(outW, cmuW, ctrl_W1, ctrl_W2, vwf);

  for (int c = 0; c < 4; ++c) {
    gemm_bt_k<64, true, false, false><<<dim3(96, 12), 256, 0, stream>>>(
        covp + (size_t)c * 48 * 256 * 64, Wih0p, bih0p, xgc, 12288, 1536, 64);
    int d = c;
    if (c & 1)
      gru_scan_k<2><<<256, 256, 0, stream>>>(xgc, Whh0p, bhh0p, h1buf,
                                             ctr + d * 1024, flg + d * 256, c * 48);
    else
      gru_scan_k<1><<<256, 256, 0, stream>>>(xgc, Whh0p, bhh0p, h1buf,
                                             ctr + d * 1024, flg + d * 256, c * 48);
  }
  for (int c = 0; c < 4; ++c) {
    gemm_bt_k<64, true, false, true><<<dim3(96, 12), 256, 0, stream>>>(
        h1buf + (size_t)(1 + c * 48) * 131072, Wih1p, bih1p, xgc, 12288, 1536, 512);
    int d = 4 + c;
    if (c & 1)
      gru_scan_k<2><<<256, 256, 0, stream>>>(xgc, Whh1p, bhh1p, cfbuf,
                                             ctr + d * 1024, flg + d * 256, c * 48);
    else
      gru_scan_k<1><<<256, 256, 0, stream>>>(xgc, Whh1p, bhh1p, cfbuf,
                                             ctr + d * 1024, flg + d * 256, c * 48);
  }
  // precompute for VAE scan (C-frag images)
  gemm_bt_k<64, false, false, true, 1><<<dim3(384, 1), 256, 0, stream>>>(
      cfbuf + 131072, featWb, feat_b, feat_img, 49152, 64, 512);
  gemm_bt_k<32, true, true, false><<<dim3(256, 1), 256, 0, stream>>>(
      labp, W1b, ctrl_b1, hdnb, 32768, 128, 32);
  gemm_bt_k<64, false, false, false, 1><<<dim3(256, 1), 256, 0, stream>>>(
      hdnb, W2b, ctrl_b2, ctrl_img, 32768, 128, 128);

  vae_k<<<16, 64, 0, stream>>>(feat_img, ctrl_img, vwf, flow_u, flow_w, flow_b,
                               outb, ctrl_b1, ctrl_b2, cmub, (float*)d_out);
}

// Round 6
// 1744.748 us; speedup vs baseline: 1.0388x; 1.0388x over previous
//
#include <hip/hip_runtime.h>
#include <stdint.h>

#define DEV static __device__ __forceinline__

using short8 = __attribute__((ext_vector_type(8))) short;
using f32x4  = __attribute__((ext_vector_type(4))) float;
using gbl_u32 = const __attribute__((address_space(1))) unsigned int;
using lds_u32 = __attribute__((address_space(3))) unsigned int;

DEV float bf2f(short s) {
  unsigned u = ((unsigned)(unsigned short)s) << 16;
  float f; __builtin_memcpy(&f, &u, 4); return f;
}
DEV short f2bf(float f) {
  unsigned u; __builtin_memcpy(&u, &f, 4);
  u = (u + 0x7fffu + ((u >> 16) & 1u)) >> 16;
  return (short)u;
}
DEV void gload_lds16(const void* g, void* l) {
  __builtin_amdgcn_global_load_lds((gbl_u32*)g, (lds_u32*)l, 16, 0, 0);
}
DEV float sigm(float x) { return 1.f / (1.f + __expf(-x)); }
DEV float tanh_f(float x) {
  float e = __expf(2.f * x);
  return 1.f - 2.f * __builtin_amdgcn_rcpf(e + 1.f);
}
// single-wave LDS write->read fence (no s_barrier, no vmcnt drain); rule #18
DEV void wave_lds_fence() {
  asm volatile("s_waitcnt lgkmcnt(0)" ::: "memory");
  __builtin_amdgcn_sched_barrier(0);
}

// ------------------------------------------------------------------
// pack kernels (unchanged)
// ------------------------------------------------------------------
__global__ void pack_cov_k(const float* __restrict__ past, const float* __restrict__ fut,
                           short* __restrict__ covp) {
  const int n = 192 * 256 * 64;
  for (int i = blockIdx.x * blockDim.x + threadIdx.x; i < n; i += gridDim.x * blockDim.x) {
    int c = i & 63, r = i >> 6;
    int b = r & 255, t = r >> 8;
    float v = (t < 128) ? past[((size_t)b * 128 + t) * 64 + c]
                        : fut[((size_t)b * 64 + (t - 128)) * 64 + c];
    covp[i] = f2bf(v);
  }
}

__global__ void pack_lab_k(const float* __restrict__ lab, short* __restrict__ labp) {
  const int n = 128 * 256 * 32;
  for (int i = blockIdx.x * blockDim.x + threadIdx.x; i < n; i += gridDim.x * blockDim.x) {
    int c = i & 31, r = i >> 5;
    int b = r & 255, t = r >> 8;
    labp[i] = f2bf(lab[((size_t)b * 128 + t) * 32 + c]);
  }
}

DEV int gru_srcrow(int pr) {
  int j = pr / 96, w = pr % 96;
  return ((w >> 5) << 9) + j * 32 + (w & 31);
}

__global__ void pack_gru_k(const float* __restrict__ Wih, const float* __restrict__ Whh,
                           const float* __restrict__ bih, const float* __restrict__ bhh,
                           int Kin, short* __restrict__ Wihp, short* __restrict__ Whhp,
                           float* __restrict__ bihp, float* __restrict__ bhhp) {
  const int nW1 = 1536 * Kin, nW2 = 1536 * 512;
  const int total = nW1 + nW2 + 3072;
  for (int idx = blockIdx.x * blockDim.x + threadIdx.x; idx < total; idx += gridDim.x * blockDim.x) {
    if (idx < nW1) {
      int pr = idx / Kin, k = idx - pr * Kin;
      Wihp[idx] = f2bf(Wih[(size_t)gru_srcrow(pr) * Kin + k]);
    } else if (idx < nW1 + nW2) {
      int ii = idx - nW1;
      int j = ii / 49152, r = ii - j * 49152;
      int i = r & 7, slot = r >> 3;
      int l = slot & 63, sf = slot >> 6;
      int kqg = sf / 6, tile = sf - kqg * 6;
      int w = tile * 16 + (l & 15);
      int k = kqg * 32 + (l >> 4) * 8 + i;
      int srow = (w >> 5) * 512 + j * 32 + (w & 31);
      Whhp[ii] = f2bf(Whh[(size_t)srow * 512 + k]);
    } else if (idx < nW1 + nW2 + 1536) {
      int pr = idx - nW1 - nW2;
      bihp[pr] = bih[gru_srcrow(pr)];
    } else {
      int pr = idx - nW1 - nW2 - 1536;
      bhhp[pr] = bhh[gru_srcrow(pr)];
    }
  }
}

__global__ void pack_misc_k(const float* __restrict__ fw, const float* __restrict__ w1,
                            const float* __restrict__ w2, short* __restrict__ fwb,
                            short* __restrict__ w1b, short* __restrict__ w2b) {
  const int n1 = 64 * 512, n2 = 128 * 32, n3 = 128 * 128;
  const int total = n1 + n2 + n3;
  for (int i = blockIdx.x * blockDim.x + threadIdx.x; i < total; i += gridDim.x * blockDim.x) {
    if (i < n1) fwb[i] = f2bf(fw[i]);
    else if (i < n1 + n2) w1b[i - n1] = f2bf(w1[i - n1]);
    else w2b[i - n1 - n2] = f2bf(w2[i - n1 - n2]);
  }
}

// vae weight frag images: 52 frags x [lane(64)][8] bf16.
__global__ void pack_vae_k(const float* __restrict__ outW, const float* __restrict__ cmuW,
                           const float* __restrict__ W1, const float* __restrict__ W2,
                           short* __restrict__ vwf) {
  const int n = 52 * 512;
  for (int i = blockIdx.x * blockDim.x + threadIdx.x; i < n; i += gridDim.x * blockDim.x) {
    int fr = i >> 9, l = (i >> 3) & 63, e = i & 7;
    int lm = l & 15, lh = l >> 4;
    float v;
    if (fr < 4) { int kt = fr >> 1, nt = fr & 1; v = outW[(nt * 16 + lm) * 64 + kt * 32 + lh * 8 + e]; }
    else if (fr < 12) { int f = fr - 4, kt = f >> 2, nt = f & 3; v = cmuW[(nt * 16 + lm) * 64 + kt * 32 + lh * 8 + e]; }
    else if (fr < 20) { int nt = fr - 12; v = W1[(nt * 16 + lm) * 32 + lh * 8 + e]; }
    else { int f = fr - 20, kt = f >> 3, nt = f & 7; v = W2[(nt * 16 + lm) * 128 + kt * 32 + lh * 8 + e]; }
    vwf[i] = f2bf(v);
  }
}

// ------------------------------------------------------------------
// GEMM (unchanged from R5)
// ------------------------------------------------------------------
template <int BK, bool OBF16, bool DOTANH, bool AFRAG, int CMODE = 0>
__global__ __launch_bounds__(256) void gemm_bt_k(
    const short* __restrict__ A, const short* __restrict__ Bw,
    const float* __restrict__ bias, void* __restrict__ Cout,
    int M, int N, int K) {
  constexpr int BM = 128, BN = 128;
  __shared__ short As[BM * BK];
  __shared__ short Bs[BN * BK];
  const int tid = threadIdx.x, lane = tid & 63;
  const int wave = tid >> 6, wm = wave >> 1, wn = wave & 1;
  const int bm = blockIdx.x, bn = blockIdx.y;
  const int lm = lane & 15, lk = (lane >> 4) * 8;
  f32x4 acc[4][4] = {};
  for (int k0 = 0; k0 < K; k0 += BK) {
    constexpr int BYTES = BM * BK * 2;
#pragma unroll
    for (int it = 0; it < BYTES / 4096; ++it) {
      int o = it * 4096 + tid * 16;
      if (AFRAG) {
        int sub = o >> 10, gl = sub >> 1, kk2 = sub & 1, inb = o & 1023;
        size_t region = ((size_t)(bm >> 1) * 16 + (bm & 1) * 8 + gl) * 16 + (k0 >> 5) + kk2;
        gload_lds16((const char*)A + region * 1024 + inb, (char*)As + (o - lane * 16));
      } else {
        int row = o / (BK * 2);
        int col = o - row * (BK * 2);
        const char* srcA = (const char*)A + (((size_t)(bm * BM + row)) * K + k0) * 2 + col;
        gload_lds16(srcA, (char*)As + (o - lane * 16));
      }
      int row = o / (BK * 2);
      int col = o - row * (BK * 2);
      int rb = bn * BN + row;
      if (rb >= N) rb = N - 1;
      const char* srcB = (const char*)Bw + (((size_t)rb) * K + k0) * 2 + col;
      gload_lds16(srcB, (char*)Bs + (o - lane * 16));
    }
    __syncthreads();
#pragma unroll
    for (int kk = 0; kk < BK / 32; ++kk) {
      short8 av[4], bv[4];
#pragma unroll
      for (int i = 0; i < 4; ++i) {
        if (AFRAG)
          av[i] = *(const short8*)((const char*)As + (((wm * 4 + i) * 2 + kk) << 10) + lane * 16);
        else
          av[i] = *(const short8*)((const char*)As + ((wm * 64 + i * 16 + lm) * BK + kk * 32 + lk) * 2);
      }
#pragma unroll
      for (int jv = 0; jv < 4; ++jv)
        bv[jv] = *(const short8*)((const char*)Bs + ((wn * 64 + jv * 16 + lm) * BK + kk * 32 + lk) * 2);
#pragma unroll
      for (int i = 0; i < 4; ++i)
#pragma unroll
        for (int jv = 0; jv < 4; ++jv)
          acc[i][jv] = __builtin_amdgcn_mfma_f32_16x16x32_bf16(av[i], bv[jv], acc[i][jv], 0, 0, 0);
    }
    __syncthreads();
  }
  if (CMODE == 1) {
    const int NT = N >> 4;
#pragma unroll
    for (int jv = 0; jv < 4; ++jv) {
      int col = bn * BN + wn * 64 + jv * 16 + lm;
      if (col >= N) continue;
      float bvl = bias[col];
#pragma unroll
      for (int i = 0; i < 4; ++i) {
        int rowblk = bm * 8 + wm * 4 + i;
        f32x4 v = acc[i][jv];
        v[0] += bvl; v[1] += bvl; v[2] += bvl; v[3] += bvl;
        *(f32x4*)((float*)Cout + (((size_t)rowblk * NT + (col >> 4)) << 8) + lane * 4) = v;
      }
    }
  } else {
#pragma unroll
    for (int jv = 0; jv < 4; ++jv) {
      int col = bn * BN + wn * 64 + jv * 16 + lm;
      if (col >= N) continue;
      float bvl = bias[col];
#pragma unroll
      for (int i = 0; i < 4; ++i) {
        int row0 = bm * BM + wm * 64 + i * 16 + (lane >> 4) * 4;
#pragma unroll
        for (int r = 0; r < 4; ++r) {
          float v = acc[i][jv][r] + bvl;
          if (DOTANH) v = tanhf(v);
          size_t off = (size_t)(row0 + r) * N + col;
          if (OBF16) ((short*)Cout)[off] = f2bf(v);
          else ((float*)Cout)[off] = v;
        }
      }
    }
  }
}

// ------------------------------------------------------------------
// GRU scan (unchanged from R4/R5, passing)
// ------------------------------------------------------------------
template <int SCHEME>
__global__ __launch_bounds__(256) void gru_scan_k(
    const short* __restrict__ xg, const short* __restrict__ Whhp,
    const float* __restrict__ bhhp, short* __restrict__ hbuf,
    unsigned int* __restrict__ ctr, unsigned int* __restrict__ flags, int t0) {
  __shared__ short Wl[96 * 512];
  __shared__ short hs[16 * 512];
  __shared__ float sc[2][16 * 101];
  __shared__ float bhs[96];
  const int tid = threadIdx.x, lane = tid & 63, wave = tid >> 6;
  const int x = blockIdx.x;
  const int g = (x & 7) + ((x >> 7) << 3);
  const int j = (x >> 3) & 15;
  unsigned int* __restrict__ myctr = ctr + g * 64;
  unsigned int* __restrict__ myflags = flags + g * 16;
  unsigned int* __restrict__ hbuf32 = (unsigned int*)hbuf;
  {
    const char* wsrc = (const char*)Whhp + (size_t)j * 98304;
#pragma unroll 4
    for (int it = 0; it < 24; ++it) {
      int o = it * 4096 + tid * 16;
      gload_lds16(wsrc + o, (char*)Wl + (o - lane * 16));
    }
    if (tid < 96) bhs[tid] = bhhp[j * 96 + tid];
  }
  const int wk = wave >> 1, wn3 = wave & 1;
  const int m = tid >> 4, up = tid & 15, u0 = up * 2;
  for (int tl = 0; tl < 48; ++tl) {
    const int t = t0 + tl;
    const char* hsrc = (const char*)hbuf + ((size_t)t * 16 + g) * 16384;
#pragma unroll
    for (int it = 0; it < 4; ++it) {
      int o = it * 4096 + tid * 16;
      gload_lds16(hsrc + o, (char*)hs + (o - lane * 16));
    }
    const unsigned int* xp = (const unsigned int*)(xg + ((size_t)tl * 256 + g * 16 + m) * 1536 + j * 96);
    unsigned int xr2 = xp[up], xz2 = xp[16 + up], xn2 = xp[32 + up];
    __syncthreads();
    f32x4 a3[3] = {};
#pragma unroll
    for (int kq = 0; kq < 8; ++kq) {
      int kqg = wk * 8 + kq;
      short8 av = *(const short8*)((const char*)hs + (kqg << 10) + lane * 16);
#pragma unroll
      for (int n = 0; n < 3; ++n) {
        short8 bv = *(const short8*)((const char*)Wl + ((kqg * 6 + wn3 * 3 + n) << 10) + lane * 16);
        a3[n] = __builtin_amdgcn_mfma_f32_16x16x32_bf16(av, bv, a3[n], 0, 0, 0);
      }
    }
#pragma unroll
    for (int n = 0; n < 3; ++n)
#pragma unroll
      for (int rr = 0; rr < 4; ++rr)
        sc[wk][((lane >> 4) * 4 + rr) * 101 + (wn3 * 3 + n) * 16 + (lane & 15)] = a3[n][rr];
    __syncthreads();
    {
      float Sr0 = sc[0][m * 101 + u0] + sc[1][m * 101 + u0];
      float Sr1 = sc[0][m * 101 + u0 + 1] + sc[1][m * 101 + u0 + 1];
      float Sz0 = sc[0][m * 101 + 32 + u0] + sc[1][m * 101 + 32 + u0];
      float Sz1 = sc[0][m * 101 + 33 + u0] + sc[1][m * 101 + 33 + u0];
      float Sn0 = sc[0][m * 101 + 64 + u0] + sc[1][m * 101 + 64 + u0];
      float Sn1 = sc[0][m * 101 + 65 + u0] + sc[1][m * 101 + 65 + u0];
      int hpa = ((j * 64 + (up >> 2) * 16 + m) << 4) + ((u0 & 7) << 1);
      unsigned int hpu = *(const unsigned int*)((const char*)hs + hpa);
      float hp0 = bf2f((short)(hpu & 0xffff)), hp1 = bf2f((short)(hpu >> 16));
      float r0 = sigm(bf2f((short)(xr2 & 0xffff)) + Sr0 + bhs[u0]);
      float r1 = sigm(bf2f((short)(xr2 >> 16)) + Sr1 + bhs[u0 + 1]);
      float z0 = sigm(bf2f((short)(xz2 & 0xffff)) + Sz0 + bhs[32 + u0]);
      float z1 = sigm(bf2f((short)(xz2 >> 16)) + Sz1 + bhs[33 + u0]);
      float n0 = tanhf(bf2f((short)(xn2 & 0xffff)) + r0 * (Sn0 + bhs[64 + u0]));
      float n1 = tanhf(bf2f((short)(xn2 >> 16)) + r1 * (Sn1 + bhs[65 + u0]));
      float h0 = (1.f - z0) * n0 + z0 * hp0;
      float h1 = (1.f - z1) * n1 + z1 * hp1;
      unsigned int hv = (unsigned int)(unsigned short)f2bf(h0) |
                        ((unsigned int)(unsigned short)f2bf(h1) << 16);
      size_t oi = ((size_t)(t + 1) * 16 + g) * 4096 +
                  (j * 64 + (up >> 2) * 16 + m) * 4 + (up & 3);
      __hip_atomic_store(hbuf32 + oi, hv, __ATOMIC_RELAXED, __HIP_MEMORY_SCOPE_AGENT);
    }
    __syncthreads();
    if constexpr (SCHEME == 1) {
      if (tid == 0) {
        __hip_atomic_fetch_add(myctr, 1u, __ATOMIC_RELAXED, __HIP_MEMORY_SCOPE_AGENT);
        const unsigned tgt = 16u * (unsigned)(tl + 1);
        int guard = 0;
        while (__hip_atomic_load(myctr, __ATOMIC_RELAXED, __HIP_MEMORY_SCOPE_AGENT) < tgt &&
               ++guard < 200000) {}
      }
    } else {
      const unsigned tgt = (unsigned)(tl + 1);
      if (tid == 0)
        __hip_atomic_store(myflags + j, tgt, __ATOMIC_RELAXED, __HIP_MEMORY_SCOPE_AGENT);
      if (tid < 16) {
        int guard = 0;
        while (__hip_atomic_load(myflags + tid, __ATOMIC_RELAXED, __HIP_MEMORY_SCOPE_AGENT) < tgt &&
               ++guard < 200000) {}
      }
    }
    __syncthreads();
  }
}

// ------------------------------------------------------------------
// VAE scan v3: 16 single-wave blocks. NO s_barrier (1 wave): LDS ordering
// via lgkmcnt-only fences -> vmcnt prefetches survive across steps.
// Past phase: pred off critical path (muA frags dumped to muprb; pred_past_k
// computes preds in parallel afterwards). ctrl/feat 2-deep register dbuf
// (named arrays + macro unroll, rule #20).
// ------------------------------------------------------------------
#define VAE_FLOW(T, FCUR)                                                   \
  _Pragma("unroll") for (int jt = 0; jt < 4; ++jt)                          \
    _Pragma("unroll") for (int r = 0; r < 4; ++r) {                         \
      float m_ = muC[jt][r];                                                 \
      float a_ = tanh_f(fw4[jt] * m_ + fb4[jt]);                             \
      muPr[jt][r] = fu4[jt] * a_ + FCUR[jt][r] + m_;                         \
      float coef_ = fu4[jt] * fw4[jt] * (1.f - a_ * a_);                     \
      varPr[jt][r] = 2.f * coef_ * varC[jt][r] + varC[jt][r] + 1.f;          \
    }

#define VAE_T1                                                               \
  _Pragma("unroll") for (int jt = 0; jt < 4; ++jt)                          \
    _Pragma("unroll") for (int r = 0; r < 4; ++r) {                         \
      int row_ = m4 * 4 + r;                                                 \
      *(short*)((char*)muA + ((row_ * 128 + (jt * 16 + c) * 2) ^ ((row_ & 7) << 4))) = f2bf(muPr[jt][r]); \
    }                                                                        \
  wave_lds_fence();                                                          \
  short8 muAf0 = *(const short8*)((const char*)muA + ((c * 128 + 0 * 64 + m4 * 16) ^ ((c & 7) << 4))); \
  short8 muAf1 = *(const short8*)((const char*)muA + ((c * 128 + 1 * 64 + m4 * 16) ^ ((c & 7) << 4)));

#define VAE_MC                                                               \
  f32x4 mcC[4] = {f32x4{0.f,0.f,0.f,0.f}, f32x4{0.f,0.f,0.f,0.f},           \
                  f32x4{0.f,0.f,0.f,0.f}, f32x4{0.f,0.f,0.f,0.f}};          \
  _Pragma("unroll") for (int nt = 0; nt < 4; ++nt) {                        \
    mcC[nt] = __builtin_amdgcn_mfma_f32_16x16x32_bf16(muAf0, cmuf[0][nt], mcC[nt], 0, 0, 0); \
    mcC[nt] = __builtin_amdgcn_mfma_f32_16x16x32_bf16(muAf1, cmuf[1][nt], mcC[nt], 0, 0, 0); \
  }

#define VAE_FUSE(T, CM, CS)                                                  \
  _Pragma("unroll") for (int jt = 0; jt < 4; ++jt)                          \
    _Pragma("unroll") for (int r = 0; r < 4; ++r) {                         \
      float vp_ = varPr[jt][r], mp_ = muPr[jt][r];                           \
      float cmv_ = (CM)[jt][r] - (mcC[jt][r] + cmub4[jt]);                   \
      float x_ = (CS)[jt][r];                                                \
      float cs_ = (x_ > 20.f) ? x_ : __logf(1.f + __expf(x_));               \
      if ((T) >= 1) {                                                        \
        size_t b_ = (size_t)(bg * 16 + m4 * 4 + r);                          \
        out[1572864 + b_ * 12224 + (size_t)((T) - 1) * 64 + jt * 16 + c] = cmv_; \
        out[4702208 + b_ * 12224 + (size_t)((T) - 1) * 64 + jt * 16 + c] = cs_;  \
      }                                                                      \
      float s_ = cs_ + vp_;                                                  \
      float rs_ = __builtin_amdgcn_rcpf(s_);                                 \
      muC[jt][r] = cs_ * rs_ * mp_ + vp_ * rs_ * cmv_;                       \
      varC[jt][r] = vp_ * cs_ * rs_;                                         \
    }

#define PAST_STEP(T, FCUR, CNXT, CCUR)                                       \
  do {                                                                       \
    f32x4 muPr[4], varPr[4];                                                 \
    VAE_FLOW(T, FCUR)                                                        \
    _Pragma("unroll") for (int jt = 0; jt < 4; ++jt)                        \
      FCUR[jt] = *(const f32x4*)(feat_img + (((size_t)((T) + 2) * 16 + bg) * 4 + jt) * 256 + l * 4); \
    if ((T) + 1 < 128) {                                                     \
      _Pragma("unroll") for (int q = 0; q < 8; ++q)                         \
        CNXT[q] = *(const f32x4*)(ctrl_img + (((size_t)((T) + 1) * 16 + bg) * 8 + q) * 256 + l * 4); \
    }                                                                        \
    VAE_T1                                                                   \
    *(short8*)(muprb + (((size_t)(T) * 16 + bg) * 2 + 0) * 512 + l * 8) = muAf0; \
    *(short8*)(muprb + (((size_t)(T) * 16 + bg) * 2 + 1) * 512 + l * 8) = muAf1; \
    VAE_MC                                                                   \
    f32x4 cmV[4], csV[4];                                                    \
    _Pragma("unroll") for (int jt = 0; jt < 4; ++jt) { cmV[jt] = CCUR[jt]; csV[jt] = CCUR[4 + jt]; } \
    VAE_FUSE(T, cmV, csV)                                                    \
  } while (0)

#define FUT_STEP(T, FCUR)                                                    \
  do {                                                                       \
    f32x4 muPr[4], varPr[4];                                                 \
    VAE_FLOW(T, FCUR)                                                        \
    if ((T) + 2 < 192) {                                                     \
      _Pragma("unroll") for (int jt = 0; jt < 4; ++jt)                      \
        FCUR[jt] = *(const f32x4*)(feat_img + (((size_t)((T) + 2) * 16 + bg) * 4 + jt) * 256 + l * 4); \
    }                                                                        \
    VAE_T1                                                                   \
    f32x4 predC[2] = {f32x4{0.f,0.f,0.f,0.f}, f32x4{0.f,0.f,0.f,0.f}};       \
    _Pragma("unroll") for (int nt = 0; nt < 2; ++nt) {                      \
      predC[nt] = __builtin_amdgcn_mfma_f32_16x16x32_bf16(muAf0, outWf[0][nt], predC[nt], 0, 0, 0); \
      predC[nt] = __builtin_amdgcn_mfma_f32_16x16x32_bf16(muAf1, outWf[1][nt], predC[nt], 0, 0, 0); \
      _Pragma("unroll") for (int r = 0; r < 4; ++r) predC[nt][r] += outb2[nt]; \
    }                                                                        \
    _Pragma("unroll") for (int nt = 0; nt < 2; ++nt)                        \
      _Pragma("unroll") for (int r = 0; r < 4; ++r)                         \
        out[(size_t)(bg * 16 + m4 * 4 + r) * 6144 + (T) * 32 + nt * 16 + c] = predC[nt][r]; \
    VAE_MC                                                                   \
    _Pragma("unroll") for (int nt = 0; nt < 2; ++nt)                        \
      _Pragma("unroll") for (int r = 0; r < 4; ++r) {                       \
        int row_ = m4 * 4 + r;                                               \
        *(short*)((char*)predA + ((row_ * 64 + (nt * 16 + c) * 2) ^ ((row_ & 3) << 4))) = f2bf(predC[nt][r]); \
      }                                                                      \
    wave_lds_fence();                                                        \
    short8 pAf = *(const short8*)((const char*)predA + ((c * 64 + m4 * 16) ^ ((c & 3) << 4))); \
    f32x4 hdnC[8];                                                           \
    _Pragma("unroll") for (int nt = 0; nt < 8; ++nt) {                      \
      short8 w1f = *(const short8*)((const char*)Wctl + nt * 1024 + l * 16); \
      f32x4 z = {0.f, 0.f, 0.f, 0.f};                                        \
      z = __builtin_amdgcn_mfma_f32_16x16x32_bf16(pAf, w1f, z, 0, 0, 0);     \
      _Pragma("unroll") for (int r = 0; r < 4; ++r) hdnC[nt][r] = tanh_f(z[r] + b1_8[nt]); \
    }                                                                        \
    _Pragma("unroll") for (int nt = 0; nt < 8; ++nt)                        \
      _Pragma("unroll") for (int r = 0; r < 4; ++r) {                       \
        int row_ = m4 * 4 + r;                                               \
        *(short*)((char*)hdnA + ((row_ * 256 + (nt * 16 + c) * 2) ^ ((row_ & 7) << 4))) = f2bf(hdnC[nt][r]); \
      }                                                                      \
    wave_lds_fence();                                                        \
    short8 hAf0 = *(const short8*)((const char*)hdnA + ((c * 256 + 0 * 64 + m4 * 16) ^ ((c & 7) << 4))); \
    short8 hAf1 = *(const short8*)((const char*)hdnA + ((c * 256 + 1 * 64 + m4 * 16) ^ ((c & 7) << 4))); \
    short8 hAf2 = *(const short8*)((const char*)hdnA + ((c * 256 + 2 * 64 + m4 * 16) ^ ((c & 7) << 4))); \
    short8 hAf3 = *(const short8*)((const char*)hdnA + ((c * 256 + 3 * 64 + m4 * 16) ^ ((c & 7) << 4))); \
    f32x4 cmV[4], csV[4];                                                    \
    _Pragma("unroll") for (int nt = 0; nt < 8; ++nt) {                      \
      f32x4 z = {0.f, 0.f, 0.f, 0.f};                                        \
      z = __builtin_amdgcn_mfma_f32_16x16x32_bf16(hAf0, *(const short8*)((const char*)Wctl + (8 + 0 * 8 + nt) * 1024 + l * 16), z, 0, 0, 0); \
      z = __builtin_amdgcn_mfma_f32_16x16x32_bf16(hAf1, *(const short8*)((const char*)Wctl + (8 + 1 * 8 + nt) * 1024 + l * 16), z, 0, 0, 0); \
      z = __builtin_amdgcn_mfma_f32_16x16x32_bf16(hAf2, *(const short8*)((const char*)Wctl + (8 + 2 * 8 + nt) * 1024 + l * 16), z, 0, 0, 0); \
      z = __builtin_amdgcn_mfma_f32_16x16x32_bf16(hAf3, *(const short8*)((const char*)Wctl + (8 + 3 * 8 + nt) * 1024 + l * 16), z, 0, 0, 0); \
      _Pragma("unroll") for (int r = 0; r < 4; ++r) {                       \
        float v_ = z[r] + b2_8[nt];                                          \
        if (nt < 4) cmV[nt][r] = v_; else csV[nt - 4][r] = v_;               \
      }                                                                      \
    }                                                                        \
    VAE_FUSE(T, cmV, csV)                                                    \
  } while (0)

__global__ __launch_bounds__(64) void vae_k(
    const float* __restrict__ feat_img, const float* __restrict__ ctrl_img,
    const short* __restrict__ vwf,
    const float* __restrict__ flow_u, const float* __restrict__ flow_w,
    const float* __restrict__ flow_b, const float* __restrict__ outb,
    const float* __restrict__ b1, const float* __restrict__ b2,
    const float* __restrict__ cmub, short* __restrict__ muprb,
    float* __restrict__ out) {
  __shared__ short Wctl[40 * 512];
  __shared__ short muA[16 * 64];
  __shared__ short predA[16 * 32];
  __shared__ short hdnA[16 * 128];
  const int l = threadIdx.x, m4 = l >> 4, c = l & 15, bg = blockIdx.x;
  {
    const char* src = (const char*)vwf + 12288;
#pragma unroll 8
    for (int it = 0; it < 40; ++it) {
      int o = it * 1024 + l * 16;
      gload_lds16(src + o, (char*)Wctl + (o - l * 16));
    }
  }
  short8 outWf[2][2], cmuf[2][4];
#pragma unroll
  for (int kt = 0; kt < 2; ++kt)
#pragma unroll
    for (int nt = 0; nt < 2; ++nt)
      outWf[kt][nt] = *(const short8*)(vwf + (kt * 2 + nt) * 512 + l * 8);
#pragma unroll
  for (int kt = 0; kt < 2; ++kt)
#pragma unroll
    for (int nt = 0; nt < 4; ++nt)
      cmuf[kt][nt] = *(const short8*)(vwf + (4 + kt * 4 + nt) * 512 + l * 8);
  float fw4[4], fu4[4], fb4[4], cmub4[4], outb2[2], b1_8[8], b2_8[8];
#pragma unroll
  for (int jt = 0; jt < 4; ++jt) {
    fw4[jt] = flow_w[jt * 16 + c]; fu4[jt] = flow_u[jt * 16 + c];
    fb4[jt] = flow_b[jt * 16 + c]; cmub4[jt] = cmub[jt * 16 + c];
  }
  outb2[0] = outb[c]; outb2[1] = outb[16 + c];
#pragma unroll
  for (int nt = 0; nt < 8; ++nt) { b1_8[nt] = b1[nt * 16 + c]; b2_8[nt] = b2[nt * 16 + c]; }
  f32x4 muC[4], varC[4], fN0[4], fN1[4], cld0[8], cld1[8];
#pragma unroll
  for (int jt = 0; jt < 4; ++jt) {
    muC[jt] = f32x4{0.f, 0.f, 0.f, 0.f};
    varC[jt] = f32x4{1.f, 1.f, 1.f, 1.f};
    fN0[jt] = *(const f32x4*)(feat_img + ((size_t)(0 * 16 + bg) * 4 + jt) * 256 + l * 4);
    fN1[jt] = *(const f32x4*)(feat_img + ((size_t)(1 * 16 + bg) * 4 + jt) * 256 + l * 4);
  }
#pragma unroll
  for (int q = 0; q < 8; ++q)
    cld0[q] = *(const f32x4*)(ctrl_img + ((size_t)(0 * 16 + bg) * 8 + q) * 256 + l * 4);
  // ---- past phase (t = 0..127): pred deferred to pred_past_k ----
  for (int t2 = 0; t2 < 128; t2 += 2) {
    PAST_STEP(t2, fN0, cld1, cld0);
    PAST_STEP(t2 + 1, fN1, cld0, cld1);
  }
  // drain Wctl's global_load_lds (and any stragglers) once
  asm volatile("s_waitcnt vmcnt(0)" ::: "memory");
  __builtin_amdgcn_sched_barrier(0);
  // ---- future phase (t = 128..191) ----
  for (int t2 = 128; t2 < 192; t2 += 2) {
    FUT_STEP(t2, fN0);
    FUT_STEP(t2 + 1, fN1);
  }
}

// ------------------------------------------------------------------
// pred_past_k: pred[t<128] = mu_pr @ outW^T + outb from saved muA frags.
// 2048 waves (one per (t, bg)); 256 blocks x 8 waves.
// ------------------------------------------------------------------
__global__ __launch_bounds__(512) void pred_past_k(
    const short* __restrict__ muprb, const short* __restrict__ vwf,
    const float* __restrict__ outb, float* __restrict__ out) {
  const int l = threadIdx.x & 63;
  const int w = blockIdx.x * 8 + (threadIdx.x >> 6);  // 0..2047
  const int t = w >> 4, bg = w & 15;
  const int m4 = l >> 4, c = l & 15;
  short8 a0 = *(const short8*)(muprb + ((size_t)w * 2 + 0) * 512 + l * 8);
  short8 a1 = *(const short8*)(muprb + ((size_t)w * 2 + 1) * 512 + l * 8);
  float outb2[2] = {outb[c], outb[16 + c]};
#pragma unroll
  for (int nt = 0; nt < 2; ++nt) {
    short8 w0 = *(const short8*)(vwf + (0 * 2 + nt) * 512 + l * 8);
    short8 w1 = *(const short8*)(vwf + (1 * 2 + nt) * 512 + l * 8);
    f32x4 p = {0.f, 0.f, 0.f, 0.f};
    p = __builtin_amdgcn_mfma_f32_16x16x32_bf16(a0, w0, p, 0, 0, 0);
    p = __builtin_amdgcn_mfma_f32_16x16x32_bf16(a1, w1, p, 0, 0, 0);
#pragma unroll
    for (int r = 0; r < 4; ++r)
      out[(size_t)(bg * 16 + m4 * 4 + r) * 6144 + t * 32 + nt * 16 + c] = p[r] + outb2[nt];
  }
}

// ------------------------------------------------------------------
extern "C" void kernel_launch(void* const* d_in, const int* in_sizes, int n_in,
                              void* d_out, int out_size, void* d_ws, size_t ws_size,
                              hipStream_t stream) {
  (void)in_sizes; (void)n_in; (void)out_size; (void)ws_size;
  const float* past_input = (const float*)d_in[0];
  const float* past_label = (const float*)d_in[1];
  const float* future_input = (const float*)d_in[2];
  const float* Wih0 = (const float*)d_in[3];
  const float* Whh0 = (const float*)d_in[4];
  const float* bih0 = (const float*)d_in[5];
  const float* bhh0 = (const float*)d_in[6];
  const float* Wih1 = (const float*)d_in[7];
  const float* Whh1 = (const float*)d_in[8];
  const float* bih1 = (const float*)d_in[9];
  const float* bhh1 = (const float*)d_in[10];
  const float* flow_u = (const float*)d_in[11];
  const float* flow_w = (const float*)d_in[12];
  const float* flow_b = (const float*)d_in[13];
  const float* feat_W = (const float*)d_in[14];
  const float* feat_b = (const float*)d_in[15];
  const float* ctrl_W1 = (const float*)d_in[16];
  const float* ctrl_b1 = (const float*)d_in[17];
  const float* ctrl_W2 = (const float*)d_in[18];
  const float* ctrl_b2 = (const float*)d_in[19];
  const float* cmuW = (const float*)d_in[20];
  const float* cmub = (const float*)d_in[21];
  const float* outW = (const float*)d_in[22];
  const float* outb = (const float*)d_in[23];

  char* ws = (char*)d_ws;
  size_t off = 0;
  auto alloc = [&](size_t bytes) -> char* {
    char* p = ws + off;
    off += (bytes + 255) & ~(size_t)255;
    return p;
  };
  short* covp  = (short*)alloc(49152ull * 64 * 2);
  short* labp  = (short*)alloc(32768ull * 32 * 2);
  short* Wih0p = (short*)alloc(1536ull * 64 * 2);
  short* Whh0p = (short*)alloc(1536ull * 512 * 2);
  short* Wih1p = (short*)alloc(1536ull * 512 * 2);
  short* Whh1p = (short*)alloc(1536ull * 512 * 2);
  float* bih0p = (float*)alloc(1536 * 4);
  float* bhh0p = (float*)alloc(1536 * 4);
  float* bih1p = (float*)alloc(1536 * 4);
  float* bhh1p = (float*)alloc(1536 * 4);
  short* featWb = (short*)alloc(64ull * 512 * 2);
  short* W1b   = (short*)alloc(128ull * 32 * 2);
  short* W2b   = (short*)alloc(128ull * 128 * 2);
  short* vwf   = (short*)alloc(52ull * 512 * 2);
  short* xgc   = (short*)alloc(48ull * 256 * 1536 * 2);
  short* h1buf = (short*)alloc(193ull * 256 * 512 * 2);
  short* cfbuf = (short*)alloc(193ull * 256 * 512 * 2);
  unsigned int* ctr = (unsigned int*)alloc(8 * 16 * 64 * 4);
  unsigned int* flg = (unsigned int*)alloc(8 * 16 * 16 * 4);
  float* feat_img = (float*)xgc;                       // overlays after scans
  short* hdnb     = (short*)((char*)xgc + 12582912);
  float* ctrl_img = (float*)((char*)xgc + 20971520);
  short* muprb    = (short*)covp;                      // covp dead after L0 gemms (4 MB need < 6.3 MB)

  hipMemsetAsync(ctr, 0, 8 * 16 * 64 * 4, stream);
  hipMemsetAsync(flg, 0, 8 * 16 * 16 * 4, stream);
  hipMemsetAsync(h1buf, 0, 256 * 512 * 2, stream);
  hipMemsetAsync(cfbuf, 0, 256 * 512 * 2, stream);

  pack_cov_k<<<2048, 256, 0, stream>>>(past_input, future_input, covp);
  pack_lab_k<<<1024, 256, 0, stream>>>(past_label, labp);
  pack_gru_k<<<1024, 256, 0, stream>>>(Wih0, Whh0, bih0, bhh0, 64, Wih0p, Whh0p, bih0p, bhh0p);
  pack_gru_k<<<1024, 256, 0, stream>>>(Wih1, Whh1, bih1, bhh1, 512, Wih1p, Whh1p, bih1p, bhh1p);
  pack_misc_k<<<64, 256, 0, stream>>>(feat_W, ctrl_W1, ctrl_W2, featWb, W1b, W2b);
  pack_vae_k<<<104, 256, 0, stream>>>(outW, cmuW, ctrl_W1, ctrl_W2, vwf);

  for (int c = 0; c < 4; ++c) {
    gemm_bt_k<64, true, false, false><<<dim3(96, 12), 256, 0, stream>>>(
        covp + (size_t)c * 48 * 256 * 64, Wih0p, bih0p, xgc, 12288, 1536, 64);
    int d = c;
    if (c & 1)
      gru_scan_k<2><<<256, 256, 0, stream>>>(xgc, Whh0p, bhh0p, h1buf,
                                             ctr + d * 1024, flg + d * 256, c * 48);
    else
      gru_scan_k<1><<<256, 256, 0, stream>>>(xgc, Whh0p, bhh0p, h1buf,
                                             ctr + d * 1024, flg + d * 256, c * 48);
  }
  for (int c = 0; c < 4; ++c) {
    gemm_bt_k<64, true, false, true><<<dim3(96, 12), 256, 0, stream>>>(
        h1buf + (size_t)(1 + c * 48) * 131072, Wih1p, bih1p, xgc, 12288, 1536, 512);
    int d = 4 + c;
    if (c & 1)
      gru_scan_k<2><<<256, 256, 0, stream>>>(xgc, Whh1p, bhh1p, cfbuf,
                                             ctr + d * 1024, flg + d * 256, c * 48);
    else
      gru_scan_k<1><<<256, 256, 0, stream>>>(xgc, Whh1p, bhh1p, cfbuf,
                                             ctr + d * 1024, flg + d * 256, c * 48);
  }
  // precompute for VAE scan (C-frag images)
  gemm_bt_k<64, false, false, true, 1><<<dim3(384, 1), 256, 0, stream>>>(
      cfbuf + 131072, featWb, feat_b, feat_img, 49152, 64, 512);
  gemm_bt_k<32, true, true, false><<<dim3(256, 1), 256, 0, stream>>>(
      labp, W1b, ctrl_b1, hdnb, 32768, 128, 32);
  gemm_bt_k<64, false, false, false, 1><<<dim3(256, 1), 256, 0, stream>>>(
      hdnb, W2b, ctrl_b2, ctrl_img, 32768, 128, 128);

  vae_k<<<16, 64, 0, stream>>>(feat_img, ctrl_img, vwf, flow_u, flow_w, flow_b,
                               outb, ctrl_b1, ctrl_b2, cmub, muprb, (float*)d_out);
  pred_past_k<<<256, 512, 0, stream>>>(muprb, vwf, outb, (float*)d_out);
}

// Round 7
// 1388.860 us; speedup vs baseline: 1.3050x; 1.2562x over previous
//
#include <hip/hip_runtime.h>
#include <stdint.h>

#define DEV static __device__ __forceinline__

using short8 = __attribute__((ext_vector_type(8))) short;
using f32x4  = __attribute__((ext_vector_type(4))) float;
using gbl_u32 = const __attribute__((address_space(1))) unsigned int;
using lds_u32 = __attribute__((address_space(3))) unsigned int;

DEV float bf2f(short s) {
  unsigned u = ((unsigned)(unsigned short)s) << 16;
  float f; __builtin_memcpy(&f, &u, 4); return f;
}
DEV short f2bf(float f) {
  unsigned u; __builtin_memcpy(&u, &f, 4);
  u = (u + 0x7fffu + ((u >> 16) & 1u)) >> 16;
  return (short)u;
}
DEV void gload_lds16(const void* g, void* l) {
  __builtin_amdgcn_global_load_lds((gbl_u32*)g, (lds_u32*)l, 16, 0, 0);
}
DEV float sigm(float x) { return 1.f / (1.f + __expf(-x)); }
DEV float tanh_f(float x) {
  float e = __expf(2.f * x);
  return 1.f - 2.f * __builtin_amdgcn_rcpf(e + 1.f);
}
// cross-wave LDS barrier WITHOUT vmcnt drain: each wave waits its own LDS ops,
// then raw s_barrier. Global-load prefetches stay in flight across it.
DEV void bar() {
  asm volatile("s_waitcnt lgkmcnt(0)" ::: "memory");
  __builtin_amdgcn_sched_barrier(0);
  __builtin_amdgcn_s_barrier();
  __builtin_amdgcn_sched_barrier(0);
}

// ------------------------------------------------------------------
// pack kernels (unchanged)
// ------------------------------------------------------------------
__global__ void pack_cov_k(const float* __restrict__ past, const float* __restrict__ fut,
                           short* __restrict__ covp) {
  const int n = 192 * 256 * 64;
  for (int i = blockIdx.x * blockDim.x + threadIdx.x; i < n; i += gridDim.x * blockDim.x) {
    int c = i & 63, r = i >> 6;
    int b = r & 255, t = r >> 8;
    float v = (t < 128) ? past[((size_t)b * 128 + t) * 64 + c]
                        : fut[((size_t)b * 64 + (t - 128)) * 64 + c];
    covp[i] = f2bf(v);
  }
}

__global__ void pack_lab_k(const float* __restrict__ lab, short* __restrict__ labp) {
  const int n = 128 * 256 * 32;
  for (int i = blockIdx.x * blockDim.x + threadIdx.x; i < n; i += gridDim.x * blockDim.x) {
    int c = i & 31, r = i >> 5;
    int b = r & 255, t = r >> 8;
    labp[i] = f2bf(lab[((size_t)b * 128 + t) * 32 + c]);
  }
}

DEV int gru_srcrow(int pr) {
  int j = pr / 96, w = pr % 96;
  return ((w >> 5) << 9) + j * 32 + (w & 31);
}

__global__ void pack_gru_k(const float* __restrict__ Wih, const float* __restrict__ Whh,
                           const float* __restrict__ bih, const float* __restrict__ bhh,
                           int Kin, short* __restrict__ Wihp, short* __restrict__ Whhp,
                           float* __restrict__ bihp, float* __restrict__ bhhp) {
  const int nW1 = 1536 * Kin, nW2 = 1536 * 512;
  const int total = nW1 + nW2 + 3072;
  for (int idx = blockIdx.x * blockDim.x + threadIdx.x; idx < total; idx += gridDim.x * blockDim.x) {
    if (idx < nW1) {
      int pr = idx / Kin, k = idx - pr * Kin;
      Wihp[idx] = f2bf(Wih[(size_t)gru_srcrow(pr) * Kin + k]);
    } else if (idx < nW1 + nW2) {
      int ii = idx - nW1;
      int j = ii / 49152, r = ii - j * 49152;
      int i = r & 7, slot = r >> 3;
      int l = slot & 63, sf = slot >> 6;
      int kqg = sf / 6, tile = sf - kqg * 6;
      int w = tile * 16 + (l & 15);
      int k = kqg * 32 + (l >> 4) * 8 + i;
      int srow = (w >> 5) * 512 + j * 32 + (w & 31);
      Whhp[ii] = f2bf(Whh[(size_t)srow * 512 + k]);
    } else if (idx < nW1 + nW2 + 1536) {
      int pr = idx - nW1 - nW2;
      bihp[pr] = bih[gru_srcrow(pr)];
    } else {
      int pr = idx - nW1 - nW2 - 1536;
      bhhp[pr] = bhh[gru_srcrow(pr)];
    }
  }
}

__global__ void pack_misc_k(const float* __restrict__ fw, const float* __restrict__ w1,
                            const float* __restrict__ w2, short* __restrict__ fwb,
                            short* __restrict__ w1b, short* __restrict__ w2b) {
  const int n1 = 64 * 512, n2 = 128 * 32, n3 = 128 * 128;
  const int total = n1 + n2 + n3;
  for (int i = blockIdx.x * blockDim.x + threadIdx.x; i < total; i += gridDim.x * blockDim.x) {
    if (i < n1) fwb[i] = f2bf(fw[i]);
    else if (i < n1 + n2) w1b[i - n1] = f2bf(w1[i - n1]);
    else w2b[i - n1 - n2] = f2bf(w2[i - n1 - n2]);
  }
}

// vae weight frag images: 52 frags x [lane(64)][8] bf16.
__global__ void pack_vae_k(const float* __restrict__ outW, const float* __restrict__ cmuW,
                           const float* __restrict__ W1, const float* __restrict__ W2,
                           short* __restrict__ vwf) {
  const int n = 52 * 512;
  for (int i = blockIdx.x * blockDim.x + threadIdx.x; i < n; i += gridDim.x * blockDim.x) {
    int fr = i >> 9, l = (i >> 3) & 63, e = i & 7;
    int lm = l & 15, lh = l >> 4;
    float v;
    if (fr < 4) { int kt = fr >> 1, nt = fr & 1; v = outW[(nt * 16 + lm) * 64 + kt * 32 + lh * 8 + e]; }
    else if (fr < 12) { int f = fr - 4, kt = f >> 2, nt = f & 3; v = cmuW[(nt * 16 + lm) * 64 + kt * 32 + lh * 8 + e]; }
    else if (fr < 20) { int nt = fr - 12; v = W1[(nt * 16 + lm) * 32 + lh * 8 + e]; }
    else { int f = fr - 20, kt = f >> 3, nt = f & 7; v = W2[(nt * 16 + lm) * 128 + kt * 32 + lh * 8 + e]; }
    vwf[i] = f2bf(v);
  }
}

// ------------------------------------------------------------------
// GEMM (unchanged from R5/R6)
// ------------------------------------------------------------------
template <int BK, bool OBF16, bool DOTANH, bool AFRAG, int CMODE = 0>
__global__ __launch_bounds__(256) void gemm_bt_k(
    const short* __restrict__ A, const short* __restrict__ Bw,
    const float* __restrict__ bias, void* __restrict__ Cout,
    int M, int N, int K) {
  constexpr int BM = 128, BN = 128;
  __shared__ short As[BM * BK];
  __shared__ short Bs[BN * BK];
  const int tid = threadIdx.x, lane = tid & 63;
  const int wave = tid >> 6, wm = wave >> 1, wn = wave & 1;
  const int bm = blockIdx.x, bn = blockIdx.y;
  const int lm = lane & 15, lk = (lane >> 4) * 8;
  f32x4 acc[4][4] = {};
  for (int k0 = 0; k0 < K; k0 += BK) {
    constexpr int BYTES = BM * BK * 2;
#pragma unroll
    for (int it = 0; it < BYTES / 4096; ++it) {
      int o = it * 4096 + tid * 16;
      if (AFRAG) {
        int sub = o >> 10, gl = sub >> 1, kk2 = sub & 1, inb = o & 1023;
        size_t region = ((size_t)(bm >> 1) * 16 + (bm & 1) * 8 + gl) * 16 + (k0 >> 5) + kk2;
        gload_lds16((const char*)A + region * 1024 + inb, (char*)As + (o - lane * 16));
      } else {
        int row = o / (BK * 2);
        int col = o - row * (BK * 2);
        const char* srcA = (const char*)A + (((size_t)(bm * BM + row)) * K + k0) * 2 + col;
        gload_lds16(srcA, (char*)As + (o - lane * 16));
      }
      int row = o / (BK * 2);
      int col = o - row * (BK * 2);
      int rb = bn * BN + row;
      if (rb >= N) rb = N - 1;
      const char* srcB = (const char*)Bw + (((size_t)rb) * K + k0) * 2 + col;
      gload_lds16(srcB, (char*)Bs + (o - lane * 16));
    }
    __syncthreads();
#pragma unroll
    for (int kk = 0; kk < BK / 32; ++kk) {
      short8 av[4], bv[4];
#pragma unroll
      for (int i = 0; i < 4; ++i) {
        if (AFRAG)
          av[i] = *(const short8*)((const char*)As + (((wm * 4 + i) * 2 + kk) << 10) + lane * 16);
        else
          av[i] = *(const short8*)((const char*)As + ((wm * 64 + i * 16 + lm) * BK + kk * 32 + lk) * 2);
      }
#pragma unroll
      for (int jv = 0; jv < 4; ++jv)
        bv[jv] = *(const short8*)((const char*)Bs + ((wn * 64 + jv * 16 + lm) * BK + kk * 32 + lk) * 2);
#pragma unroll
      for (int i = 0; i < 4; ++i)
#pragma unroll
        for (int jv = 0; jv < 4; ++jv)
          acc[i][jv] = __builtin_amdgcn_mfma_f32_16x16x32_bf16(av[i], bv[jv], acc[i][jv], 0, 0, 0);
    }
    __syncthreads();
  }
  if (CMODE == 1) {
    const int NT = N >> 4;
#pragma unroll
    for (int jv = 0; jv < 4; ++jv) {
      int col = bn * BN + wn * 64 + jv * 16 + lm;
      if (col >= N) continue;
      float bvl = bias[col];
#pragma unroll
      for (int i = 0; i < 4; ++i) {
        int rowblk = bm * 8 + wm * 4 + i;
        f32x4 v = acc[i][jv];
        v[0] += bvl; v[1] += bvl; v[2] += bvl; v[3] += bvl;
        *(f32x4*)((float*)Cout + (((size_t)rowblk * NT + (col >> 4)) << 8) + lane * 4) = v;
      }
    }
  } else {
#pragma unroll
    for (int jv = 0; jv < 4; ++jv) {
      int col = bn * BN + wn * 64 + jv * 16 + lm;
      if (col >= N) continue;
      float bvl = bias[col];
#pragma unroll
      for (int i = 0; i < 4; ++i) {
        int row0 = bm * BM + wm * 64 + i * 16 + (lane >> 4) * 4;
#pragma unroll
        for (int r = 0; r < 4; ++r) {
          float v = acc[i][jv][r] + bvl;
          if (DOTANH) v = tanhf(v);
          size_t off = (size_t)(row0 + r) * N + col;
          if (OBF16) ((short*)Cout)[off] = f2bf(v);
          else ((float*)Cout)[off] = v;
        }
      }
    }
  }
}

// ------------------------------------------------------------------
// GRU scan (unchanged from R4/R6, passing)
// ------------------------------------------------------------------
template <int SCHEME>
__global__ __launch_bounds__(256) void gru_scan_k(
    const short* __restrict__ xg, const short* __restrict__ Whhp,
    const float* __restrict__ bhhp, short* __restrict__ hbuf,
    unsigned int* __restrict__ ctr, unsigned int* __restrict__ flags, int t0) {
  __shared__ short Wl[96 * 512];
  __shared__ short hs[16 * 512];
  __shared__ float sc[2][16 * 101];
  __shared__ float bhs[96];
  const int tid = threadIdx.x, lane = tid & 63, wave = tid >> 6;
  const int x = blockIdx.x;
  const int g = (x & 7) + ((x >> 7) << 3);
  const int j = (x >> 3) & 15;
  unsigned int* __restrict__ myctr = ctr + g * 64;
  unsigned int* __restrict__ myflags = flags + g * 16;
  unsigned int* __restrict__ hbuf32 = (unsigned int*)hbuf;
  {
    const char* wsrc = (const char*)Whhp + (size_t)j * 98304;
#pragma unroll 4
    for (int it = 0; it < 24; ++it) {
      int o = it * 4096 + tid * 16;
      gload_lds16(wsrc + o, (char*)Wl + (o - lane * 16));
    }
    if (tid < 96) bhs[tid] = bhhp[j * 96 + tid];
  }
  const int wk = wave >> 1, wn3 = wave & 1;
  const int m = tid >> 4, up = tid & 15, u0 = up * 2;
  for (int tl = 0; tl < 48; ++tl) {
    const int t = t0 + tl;
    const char* hsrc = (const char*)hbuf + ((size_t)t * 16 + g) * 16384;
#pragma unroll
    for (int it = 0; it < 4; ++it) {
      int o = it * 4096 + tid * 16;
      gload_lds16(hsrc + o, (char*)hs + (o - lane * 16));
    }
    const unsigned int* xp = (const unsigned int*)(xg + ((size_t)tl * 256 + g * 16 + m) * 1536 + j * 96);
    unsigned int xr2 = xp[up], xz2 = xp[16 + up], xn2 = xp[32 + up];
    __syncthreads();
    f32x4 a3[3] = {};
#pragma unroll
    for (int kq = 0; kq < 8; ++kq) {
      int kqg = wk * 8 + kq;
      short8 av = *(const short8*)((const char*)hs + (kqg << 10) + lane * 16);
#pragma unroll
      for (int n = 0; n < 3; ++n) {
        short8 bv = *(const short8*)((const char*)Wl + ((kqg * 6 + wn3 * 3 + n) << 10) + lane * 16);
        a3[n] = __builtin_amdgcn_mfma_f32_16x16x32_bf16(av, bv, a3[n], 0, 0, 0);
      }
    }
#pragma unroll
    for (int n = 0; n < 3; ++n)
#pragma unroll
      for (int rr = 0; rr < 4; ++rr)
        sc[wk][((lane >> 4) * 4 + rr) * 101 + (wn3 * 3 + n) * 16 + (lane & 15)] = a3[n][rr];
    __syncthreads();
    {
      float Sr0 = sc[0][m * 101 + u0] + sc[1][m * 101 + u0];
      float Sr1 = sc[0][m * 101 + u0 + 1] + sc[1][m * 101 + u0 + 1];
      float Sz0 = sc[0][m * 101 + 32 + u0] + sc[1][m * 101 + 32 + u0];
      float Sz1 = sc[0][m * 101 + 33 + u0] + sc[1][m * 101 + 33 + u0];
      float Sn0 = sc[0][m * 101 + 64 + u0] + sc[1][m * 101 + 64 + u0];
      float Sn1 = sc[0][m * 101 + 65 + u0] + sc[1][m * 101 + 65 + u0];
      int hpa = ((j * 64 + (up >> 2) * 16 + m) << 4) + ((u0 & 7) << 1);
      unsigned int hpu = *(const unsigned int*)((const char*)hs + hpa);
      float hp0 = bf2f((short)(hpu & 0xffff)), hp1 = bf2f((short)(hpu >> 16));
      float r0 = sigm(bf2f((short)(xr2 & 0xffff)) + Sr0 + bhs[u0]);
      float r1 = sigm(bf2f((short)(xr2 >> 16)) + Sr1 + bhs[u0 + 1]);
      float z0 = sigm(bf2f((short)(xz2 & 0xffff)) + Sz0 + bhs[32 + u0]);
      float z1 = sigm(bf2f((short)(xz2 >> 16)) + Sz1 + bhs[33 + u0]);
      float n0 = tanhf(bf2f((short)(xn2 & 0xffff)) + r0 * (Sn0 + bhs[64 + u0]));
      float n1 = tanhf(bf2f((short)(xn2 >> 16)) + r1 * (Sn1 + bhs[65 + u0]));
      float h0 = (1.f - z0) * n0 + z0 * hp0;
      float h1 = (1.f - z1) * n1 + z1 * hp1;
      unsigned int hv = (unsigned int)(unsigned short)f2bf(h0) |
                        ((unsigned int)(unsigned short)f2bf(h1) << 16);
      size_t oi = ((size_t)(t + 1) * 16 + g) * 4096 +
                  (j * 64 + (up >> 2) * 16 + m) * 4 + (up & 3);
      __hip_atomic_store(hbuf32 + oi, hv, __ATOMIC_RELAXED, __HIP_MEMORY_SCOPE_AGENT);
    }
    __syncthreads();
    if constexpr (SCHEME == 1) {
      if (tid == 0) {
        __hip_atomic_fetch_add(myctr, 1u, __ATOMIC_RELAXED, __HIP_MEMORY_SCOPE_AGENT);
        const unsigned tgt = 16u * (unsigned)(tl + 1);
        int guard = 0;
        while (__hip_atomic_load(myctr, __ATOMIC_RELAXED, __HIP_MEMORY_SCOPE_AGENT) < tgt &&
               ++guard < 200000) {}
      }
    } else {
      const unsigned tgt = (unsigned)(tl + 1);
      if (tid == 0)
        __hip_atomic_store(myflags + j, tgt, __ATOMIC_RELAXED, __HIP_MEMORY_SCOPE_AGENT);
      if (tid < 16) {
        int guard = 0;
        while (__hip_atomic_load(myflags + tid, __ATOMIC_RELAXED, __HIP_MEMORY_SCOPE_AGENT) < tgt &&
               ++guard < 200000) {}
      }
    }
    __syncthreads();
  }
}

// ------------------------------------------------------------------
// VAE scan v4: 16 blocks x 4 waves. Wave w owns column-tile jt=w of the
// D=64 state (4 f32/lane). Matvecs split by output tile across waves; LDS
// transpose buffers shared; raw s_barrier + per-wave lgkmcnt (no vmcnt
// drain -> global prefetches survive). Chain work per wave is 1/4 of v3.
// ------------------------------------------------------------------
#define PAST_STEP(T, FN, CMR, CSR)                                           \
  do {                                                                       \
    f32x4 muPr, varPr;                                                       \
    _Pragma("unroll") for (int r = 0; r < 4; ++r) {                          \
      float m_ = muC[r];                                                     \
      float a_ = tanh_f(fw1 * m_ + fb1);                                     \
      muPr[r] = fu1 * a_ + FN[r] + m_;                                       \
      float cf_ = fu1 * fw1 * (1.f - a_ * a_);                               \
      varPr[r] = 2.f * cf_ * varC[r] + varC[r] + 1.f;                        \
    }                                                                        \
    f32x4 cmNow = CMR, csNow = CSR;                                          \
    FN = *(const f32x4*)(feat_img + (((size_t)((T) + 2) * 16 + bg) * 4 + w) * 256 + l * 4); \
    if ((T) + 2 < 128) {                                                     \
      CMR = *(const f32x4*)(ctrl_img + (((size_t)((T) + 2) * 16 + bg) * 8 + w) * 256 + l * 4); \
      CSR = *(const f32x4*)(ctrl_img + (((size_t)((T) + 2) * 16 + bg) * 8 + 4 + w) * 256 + l * 4); \
    }                                                                        \
    _Pragma("unroll") for (int r = 0; r < 4; ++r) {                          \
      int row_ = m4 * 4 + r;                                                 \
      *(short*)((char*)muA + ((row_ * 128 + (w * 16 + c) * 2) ^ ((row_ & 7) << 4))) = f2bf(muPr[r]); \
    }                                                                        \
    bar();                                                                   \
    short8 muAf0 = *(const short8*)((const char*)muA + ((c * 128 + m4 * 16) ^ ((c & 7) << 4))); \
    short8 muAf1 = *(const short8*)((const char*)muA + ((c * 128 + 64 + m4 * 16) ^ ((c & 7) << 4))); \
    if (w == 0) *(short8*)(muprb + (((size_t)(T) * 16 + bg) * 2) * 512 + l * 8) = muAf0; \
    if (w == 1) *(short8*)(muprb + (((size_t)(T) * 16 + bg) * 2 + 1) * 512 + l * 8) = muAf1; \
    f32x4 mcC = {0.f, 0.f, 0.f, 0.f};                                        \
    mcC = __builtin_amdgcn_mfma_f32_16x16x32_bf16(muAf0, cmuf0, mcC, 0, 0, 0); \
    mcC = __builtin_amdgcn_mfma_f32_16x16x32_bf16(muAf1, cmuf1, mcC, 0, 0, 0); \
    bar();                                                                   \
    _Pragma("unroll") for (int r = 0; r < 4; ++r) {                          \
      float vp_ = varPr[r], mp_ = muPr[r];                                   \
      float cmv_ = cmNow[r] - (mcC[r] + cmub1);                              \
      float x_ = csNow[r];                                                   \
      float cs_ = (x_ > 20.f) ? x_ : __logf(1.f + __expf(x_));               \
      if ((T) >= 1) {                                                        \
        size_t b_ = (size_t)(bg * 16 + m4 * 4 + r);                          \
        out[1572864 + b_ * 12224 + (size_t)((T) - 1) * 64 + w * 16 + c] = cmv_; \
        out[4702208 + b_ * 12224 + (size_t)((T) - 1) * 64 + w * 16 + c] = cs_;  \
      }                                                                      \
      float s_ = cs_ + vp_;                                                  \
      float rs_ = __builtin_amdgcn_rcpf(s_);                                 \
      muC[r] = cs_ * rs_ * mp_ + vp_ * rs_ * cmv_;                           \
      varC[r] = vp_ * cs_ * rs_;                                             \
    }                                                                        \
  } while (0)

#define FUT_STEP(T, FN)                                                      \
  do {                                                                       \
    f32x4 muPr, varPr;                                                       \
    _Pragma("unroll") for (int r = 0; r < 4; ++r) {                          \
      float m_ = muC[r];                                                     \
      float a_ = tanh_f(fw1 * m_ + fb1);                                     \
      muPr[r] = fu1 * a_ + FN[r] + m_;                                       \
      float cf_ = fu1 * fw1 * (1.f - a_ * a_);                               \
      varPr[r] = 2.f * cf_ * varC[r] + varC[r] + 1.f;                        \
    }                                                                        \
    if ((T) + 2 < 192)                                                       \
      FN = *(const f32x4*)(feat_img + (((size_t)((T) + 2) * 16 + bg) * 4 + w) * 256 + l * 4); \
    _Pragma("unroll") for (int r = 0; r < 4; ++r) {                          \
      int row_ = m4 * 4 + r;                                                 \
      *(short*)((char*)muA + ((row_ * 128 + (w * 16 + c) * 2) ^ ((row_ & 7) << 4))) = f2bf(muPr[r]); \
    }                                                                        \
    bar();                                                                   \
    short8 muAf0 = *(const short8*)((const char*)muA + ((c * 128 + m4 * 16) ^ ((c & 7) << 4))); \
    short8 muAf1 = *(const short8*)((const char*)muA + ((c * 128 + 64 + m4 * 16) ^ ((c & 7) << 4))); \
    f32x4 mcC = {0.f, 0.f, 0.f, 0.f};                                        \
    mcC = __builtin_amdgcn_mfma_f32_16x16x32_bf16(muAf0, cmuf0, mcC, 0, 0, 0); \
    mcC = __builtin_amdgcn_mfma_f32_16x16x32_bf16(muAf1, cmuf1, mcC, 0, 0, 0); \
    if (w < 2) {                                                             \
      f32x4 predC = {0.f, 0.f, 0.f, 0.f};                                    \
      predC = __builtin_amdgcn_mfma_f32_16x16x32_bf16(muAf0, outWf0, predC, 0, 0, 0); \
      predC = __builtin_amdgcn_mfma_f32_16x16x32_bf16(muAf1, outWf1, predC, 0, 0, 0); \
      _Pragma("unroll") for (int r = 0; r < 4; ++r) {                        \
        float pv_ = predC[r] + outb1;                                        \
        out[(size_t)(bg * 16 + m4 * 4 + r) * 6144 + (T) * 32 + w * 16 + c] = pv_; \
        int row_ = m4 * 4 + r;                                               \
        *(short*)((char*)predA + ((row_ * 64 + (w * 16 + c) * 2) ^ ((row_ & 3) << 4))) = f2bf(pv_); \
      }                                                                      \
    }                                                                        \
    bar();                                                                   \
    short8 pAf = *(const short8*)((const char*)predA + ((c * 64 + m4 * 16) ^ ((c & 3) << 4))); \
    f32x4 z0 = {0.f, 0.f, 0.f, 0.f}, z1 = {0.f, 0.f, 0.f, 0.f};              \
    z0 = __builtin_amdgcn_mfma_f32_16x16x32_bf16(pAf, *(const short8*)((const char*)Wctl + (2 * w) * 1024 + l * 16), z0, 0, 0, 0); \
    z1 = __builtin_amdgcn_mfma_f32_16x16x32_bf16(pAf, *(const short8*)((const char*)Wctl + (2 * w + 1) * 1024 + l * 16), z1, 0, 0, 0); \
    _Pragma("unroll") for (int r = 0; r < 4; ++r) {                          \
      int row_ = m4 * 4 + r;                                                 \
      *(short*)((char*)hdnA + ((row_ * 256 + ((2 * w) * 16 + c) * 2) ^ ((row_ & 7) << 4))) = f2bf(tanh_f(z0[r] + b1a)); \
      *(short*)((char*)hdnA + ((row_ * 256 + ((2 * w + 1) * 16 + c) * 2) ^ ((row_ & 7) << 4))) = f2bf(tanh_f(z1[r] + b1b)); \
    }                                                                        \
    bar();                                                                   \
    short8 hAf0 = *(const short8*)((const char*)hdnA + ((c * 256 + 0 * 64 + m4 * 16) ^ ((c & 7) << 4))); \
    short8 hAf1 = *(const short8*)((const char*)hdnA + ((c * 256 + 1 * 64 + m4 * 16) ^ ((c & 7) << 4))); \
    short8 hAf2 = *(const short8*)((const char*)hdnA + ((c * 256 + 2 * 64 + m4 * 16) ^ ((c & 7) << 4))); \
    short8 hAf3 = *(const short8*)((const char*)hdnA + ((c * 256 + 3 * 64 + m4 * 16) ^ ((c & 7) << 4))); \
    f32x4 zcm = {0.f, 0.f, 0.f, 0.f}, zcs = {0.f, 0.f, 0.f, 0.f};            \
    zcm = __builtin_amdgcn_mfma_f32_16x16x32_bf16(hAf0, *(const short8*)((const char*)Wctl + (8 + 0 * 8 + w) * 1024 + l * 16), zcm, 0, 0, 0); \
    zcm = __builtin_amdgcn_mfma_f32_16x16x32_bf16(hAf1, *(const short8*)((const char*)Wctl + (8 + 1 * 8 + w) * 1024 + l * 16), zcm, 0, 0, 0); \
    zcm = __builtin_amdgcn_mfma_f32_16x16x32_bf16(hAf2, *(const short8*)((const char*)Wctl + (8 + 2 * 8 + w) * 1024 + l * 16), zcm, 0, 0, 0); \
    zcm = __builtin_amdgcn_mfma_f32_16x16x32_bf16(hAf3, *(const short8*)((const char*)Wctl + (8 + 3 * 8 + w) * 1024 + l * 16), zcm, 0, 0, 0); \
    zcs = __builtin_amdgcn_mfma_f32_16x16x32_bf16(hAf0, *(const short8*)((const char*)Wctl + (8 + 0 * 8 + 4 + w) * 1024 + l * 16), zcs, 0, 0, 0); \
    zcs = __builtin_amdgcn_mfma_f32_16x16x32_bf16(hAf1, *(const short8*)((const char*)Wctl + (8 + 1 * 8 + 4 + w) * 1024 + l * 16), zcs, 0, 0, 0); \
    zcs = __builtin_amdgcn_mfma_f32_16x16x32_bf16(hAf2, *(const short8*)((const char*)Wctl + (8 + 2 * 8 + 4 + w) * 1024 + l * 16), zcs, 0, 0, 0); \
    zcs = __builtin_amdgcn_mfma_f32_16x16x32_bf16(hAf3, *(const short8*)((const char*)Wctl + (8 + 3 * 8 + 4 + w) * 1024 + l * 16), zcs, 0, 0, 0); \
    bar();                                                                   \
    _Pragma("unroll") for (int r = 0; r < 4; ++r) {                          \
      float vp_ = varPr[r], mp_ = muPr[r];                                   \
      float cmv_ = (zcm[r] + b2cm) - (mcC[r] + cmub1);                       \
      float x_ = zcs[r] + b2cs;                                              \
      float cs_ = (x_ > 20.f) ? x_ : __logf(1.f + __expf(x_));               \
      size_t b_ = (size_t)(bg * 16 + m4 * 4 + r);                            \
      out[1572864 + b_ * 12224 + (size_t)((T) - 1) * 64 + w * 16 + c] = cmv_; \
      out[4702208 + b_ * 12224 + (size_t)((T) - 1) * 64 + w * 16 + c] = cs_;  \
      float s_ = cs_ + vp_;                                                  \
      float rs_ = __builtin_amdgcn_rcpf(s_);                                 \
      muC[r] = cs_ * rs_ * mp_ + vp_ * rs_ * cmv_;                           \
      varC[r] = vp_ * cs_ * rs_;                                             \
    }                                                                        \
  } while (0)

__global__ __launch_bounds__(256) void vae_k(
    const float* __restrict__ feat_img, const float* __restrict__ ctrl_img,
    const short* __restrict__ vwf,
    const float* __restrict__ flow_u, const float* __restrict__ flow_w,
    const float* __restrict__ flow_b, const float* __restrict__ outb,
    const float* __restrict__ b1, const float* __restrict__ b2,
    const float* __restrict__ cmub, short* __restrict__ muprb,
    float* __restrict__ out) {
  __shared__ short Wctl[40 * 512];
  __shared__ short muA[16 * 64];
  __shared__ short predA[16 * 32];
  __shared__ short hdnA[16 * 128];
  const int tid = threadIdx.x, l = tid & 63, w = tid >> 6;
  const int m4 = l >> 4, c = l & 15, bg = blockIdx.x;
  {
    const char* src = (const char*)vwf + 12288;
#pragma unroll
    for (int it = 0; it < 10; ++it) {
      int o = it * 4096 + tid * 16;
      gload_lds16(src + o, (char*)Wctl + (o - l * 16));
    }
  }
  // per-wave weight frags / consts
  short8 cmuf0 = *(const short8*)(vwf + (4 + w) * 512 + l * 8);
  short8 cmuf1 = *(const short8*)(vwf + (8 + w) * 512 + l * 8);
  short8 outWf0 = *(const short8*)(vwf + ((w & 1)) * 512 + l * 8);
  short8 outWf1 = *(const short8*)(vwf + (2 + (w & 1)) * 512 + l * 8);
  float fw1 = flow_w[w * 16 + c], fu1 = flow_u[w * 16 + c];
  float fb1 = flow_b[w * 16 + c], cmub1 = cmub[w * 16 + c];
  float outb1 = outb[(w & 1) * 16 + c];
  float b1a = b1[(2 * w) * 16 + c], b1b = b1[(2 * w + 1) * 16 + c];
  float b2cm = b2[w * 16 + c], b2cs = b2[(4 + w) * 16 + c];
  f32x4 muC = {0.f, 0.f, 0.f, 0.f}, varC = {1.f, 1.f, 1.f, 1.f};
  f32x4 fN0 = *(const f32x4*)(feat_img + ((size_t)bg * 4 + w) * 256 + l * 4);
  f32x4 fN1 = *(const f32x4*)(feat_img + ((size_t)(16 + bg) * 4 + w) * 256 + l * 4);
  f32x4 cmA = *(const f32x4*)(ctrl_img + ((size_t)bg * 8 + w) * 256 + l * 4);
  f32x4 csA = *(const f32x4*)(ctrl_img + ((size_t)bg * 8 + 4 + w) * 256 + l * 4);
  f32x4 cmB = *(const f32x4*)(ctrl_img + ((size_t)(16 + bg) * 8 + w) * 256 + l * 4);
  f32x4 csB = *(const f32x4*)(ctrl_img + ((size_t)(16 + bg) * 8 + 4 + w) * 256 + l * 4);
  __syncthreads();
  // ---- past phase (t = 0..127); pred deferred to pred_past_k ----
  for (int t2 = 0; t2 < 128; t2 += 2) {
    PAST_STEP(t2, fN0, cmA, csA);
    PAST_STEP(t2 + 1, fN1, cmB, csB);
  }
  // drain Wctl staging once; all waves synced before first Wctl read
  asm volatile("s_waitcnt vmcnt(0)" ::: "memory");
  __builtin_amdgcn_sched_barrier(0);
  __builtin_amdgcn_s_barrier();
  // ---- future phase (t = 128..191) ----
  for (int t2 = 128; t2 < 192; t2 += 2) {
    FUT_STEP(t2, fN0);
    FUT_STEP(t2 + 1, fN1);
  }
}

// ------------------------------------------------------------------
// pred_past_k (unchanged)
// ------------------------------------------------------------------
__global__ __launch_bounds__(512) void pred_past_k(
    const short* __restrict__ muprb, const short* __restrict__ vwf,
    const float* __restrict__ outb, float* __restrict__ out) {
  const int l = threadIdx.x & 63;
  const int w = blockIdx.x * 8 + (threadIdx.x >> 6);
  const int t = w >> 4, bg = w & 15;
  const int m4 = l >> 4, c = l & 15;
  short8 a0 = *(const short8*)(muprb + ((size_t)w * 2 + 0) * 512 + l * 8);
  short8 a1 = *(const short8*)(muprb + ((size_t)w * 2 + 1) * 512 + l * 8);
  float outb2[2] = {outb[c], outb[16 + c]};
#pragma unroll
  for (int nt = 0; nt < 2; ++nt) {
    short8 w0 = *(const short8*)(vwf + (0 * 2 + nt) * 512 + l * 8);
    short8 w1 = *(const short8*)(vwf + (1 * 2 + nt) * 512 + l * 8);
    f32x4 p = {0.f, 0.f, 0.f, 0.f};
    p = __builtin_amdgcn_mfma_f32_16x16x32_bf16(a0, w0, p, 0, 0, 0);
    p = __builtin_amdgcn_mfma_f32_16x16x32_bf16(a1, w1, p, 0, 0, 0);
#pragma unroll
    for (int r = 0; r < 4; ++r)
      out[(size_t)(bg * 16 + m4 * 4 + r) * 6144 + t * 32 + nt * 16 + c] = p[r] + outb2[nt];
  }
}

// ------------------------------------------------------------------
extern "C" void kernel_launch(void* const* d_in, const int* in_sizes, int n_in,
                              void* d_out, int out_size, void* d_ws, size_t ws_size,
                              hipStream_t stream) {
  (void)in_sizes; (void)n_in; (void)out_size; (void)ws_size;
  const float* past_input = (const float*)d_in[0];
  const float* past_label = (const float*)d_in[1];
  const float* future_input = (const float*)d_in[2];
  const float* Wih0 = (const float*)d_in[3];
  const float* Whh0 = (const float*)d_in[4];
  const float* bih0 = (const float*)d_in[5];
  const float* bhh0 = (const float*)d_in[6];
  const float* Wih1 = (const float*)d_in[7];
  const float* Whh1 = (const float*)d_in[8];
  const float* bih1 = (const float*)d_in[9];
  const float* bhh1 = (const float*)d_in[10];
  const float* flow_u = (const float*)d_in[11];
  const float* flow_w = (const float*)d_in[12];
  const float* flow_b = (const float*)d_in[13];
  const float* feat_W = (const float*)d_in[14];
  const float* feat_b = (const float*)d_in[15];
  const float* ctrl_W1 = (const float*)d_in[16];
  const float* ctrl_b1 = (const float*)d_in[17];
  const float* ctrl_W2 = (const float*)d_in[18];
  const float* ctrl_b2 = (const float*)d_in[19];
  const float* cmuW = (const float*)d_in[20];
  const float* cmub = (const float*)d_in[21];
  const float* outW = (const float*)d_in[22];
  const float* outb = (const float*)d_in[23];

  char* ws = (char*)d_ws;
  size_t off = 0;
  auto alloc = [&](size_t bytes) -> char* {
    char* p = ws + off;
    off += (bytes + 255) & ~(size_t)255;
    return p;
  };
  short* covp  = (short*)alloc(49152ull * 64 * 2);
  short* labp  = (short*)alloc(32768ull * 32 * 2);
  short* Wih0p = (short*)alloc(1536ull * 64 * 2);
  short* Whh0p = (short*)alloc(1536ull * 512 * 2);
  short* Wih1p = (short*)alloc(1536ull * 512 * 2);
  short* Whh1p = (short*)alloc(1536ull * 512 * 2);
  float* bih0p = (float*)alloc(1536 * 4);
  float* bhh0p = (float*)alloc(1536 * 4);
  float* bih1p = (float*)alloc(1536 * 4);
  float* bhh1p = (float*)alloc(1536 * 4);
  short* featWb = (short*)alloc(64ull * 512 * 2);
  short* W1b   = (short*)alloc(128ull * 32 * 2);
  short* W2b   = (short*)alloc(128ull * 128 * 2);
  short* vwf   = (short*)alloc(52ull * 512 * 2);
  short* xgc   = (short*)alloc(48ull * 256 * 1536 * 2);
  short* h1buf = (short*)alloc(193ull * 256 * 512 * 2);
  short* cfbuf = (short*)alloc(193ull * 256 * 512 * 2);
  unsigned int* ctr = (unsigned int*)alloc(8 * 16 * 64 * 4);
  unsigned int* flg = (unsigned int*)alloc(8 * 16 * 16 * 4);
  float* feat_img = (float*)xgc;
  short* hdnb     = (short*)((char*)xgc + 12582912);
  float* ctrl_img = (float*)((char*)xgc + 20971520);
  short* muprb    = (short*)covp;  // covp dead after L0 gemms

  hipMemsetAsync(ctr, 0, 8 * 16 * 64 * 4, stream);
  hipMemsetAsync(flg, 0, 8 * 16 * 16 * 4, stream);
  hipMemsetAsync(h1buf, 0, 256 * 512 * 2, stream);
  hipMemsetAsync(cfbuf, 0, 256 * 512 * 2, stream);

  pack_cov_k<<<2048, 256, 0, stream>>>(past_input, future_input, covp);
  pack_lab_k<<<1024, 256, 0, stream>>>(past_label, labp);
  pack_gru_k<<<1024, 256, 0, stream>>>(Wih0, Whh0, bih0, bhh0, 64, Wih0p, Whh0p, bih0p, bhh0p);
  pack_gru_k<<<1024, 256, 0, stream>>>(Wih1, Whh1, bih1, bhh1, 512, Wih1p, Whh1p, bih1p, bhh1p);
  pack_misc_k<<<64, 256, 0, stream>>>(feat_W, ctrl_W1, ctrl_W2, featWb, W1b, W2b);
  pack_vae_k<<<104, 256, 0, stream>>>(outW, cmuW, ctrl_W1, ctrl_W2, vwf);

  for (int c = 0; c < 4; ++c) {
    gemm_bt_k<64, true, false, false><<<dim3(96, 12), 256, 0, stream>>>(
        covp + (size_t)c * 48 * 256 * 64, Wih0p, bih0p, xgc, 12288, 1536, 64);
    int d = c;
    if (c & 1)
      gru_scan_k<2><<<256, 256, 0, stream>>>(xgc, Whh0p, bhh0p, h1buf,
                                             ctr + d * 1024, flg + d * 256, c * 48);
    else
      gru_scan_k<1><<<256, 256, 0, stream>>>(xgc, Whh0p, bhh0p, h1buf,
                                             ctr + d * 1024, flg + d * 256, c * 48);
  }
  for (int c = 0; c < 4; ++c) {
    gemm_bt_k<64, true, false, true><<<dim3(96, 12), 256, 0, stream>>>(
        h1buf + (size_t)(1 + c * 48) * 131072, Wih1p, bih1p, xgc, 12288, 1536, 512);
    int d = 4 + c;
    if (c & 1)
      gru_scan_k<2><<<256, 256, 0, stream>>>(xgc, Whh1p, bhh1p, cfbuf,
                                             ctr + d * 1024, flg + d * 256, c * 48);
    else
      gru_scan_k<1><<<256, 256, 0, stream>>>(xgc, Whh1p, bhh1p, cfbuf,
                                             ctr + d * 1024, flg + d * 256, c * 48);
  }
  gemm_bt_k<64, false, false, true, 1><<<dim3(384, 1), 256, 0, stream>>>(
      cfbuf + 131072, featWb, feat_b, feat_img, 49152, 64, 512);
  gemm_bt_k<32, true, true, false><<<dim3(256, 1), 256, 0, stream>>>(
      labp, W1b, ctrl_b1, hdnb, 32768, 128, 32);
  gemm_bt_k<64, false, false, false, 1><<<dim3(256, 1), 256, 0, stream>>>(
      hdnb, W2b, ctrl_b2, ctrl_img, 32768, 128, 128);

  vae_k<<<16, 256, 0, stream>>>(feat_img, ctrl_img, vwf, flow_u, flow_w, flow_b,
                                outb, ctrl_b1, ctrl_b2, cmub, muprb, (float*)d_out);
  pred_past_k<<<256, 512, 0, stream>>>(muprb, vwf, outb, (float*)d_out);
}

// Round 9
// 1348.822 us; speedup vs baseline: 1.3438x; 1.0297x over previous
//
#include <hip/hip_runtime.h>
#include <stdint.h>

#define DEV static __device__ __forceinline__

using short8 = __attribute__((ext_vector_type(8))) short;
using f32x4  = __attribute__((ext_vector_type(4))) float;
using gbl_u32 = const __attribute__((address_space(1))) unsigned int;
using lds_u32 = __attribute__((address_space(3))) unsigned int;

DEV float bf2f(short s) {
  unsigned u = ((unsigned)(unsigned short)s) << 16;
  float f; __builtin_memcpy(&f, &u, 4); return f;
}
DEV short f2bf(float f) {
  unsigned u; __builtin_memcpy(&u, &f, 4);
  u = (u + 0x7fffu + ((u >> 16) & 1u)) >> 16;
  return (short)u;
}
DEV void gload_lds16(const void* g, void* l) {
  __builtin_amdgcn_global_load_lds((gbl_u32*)g, (lds_u32*)l, 16, 0, 0);
}
DEV float sigm(float x) { return 1.f / (1.f + __expf(-x)); }
DEV float tanh_f(float x) {
  float e = __expf(2.f * x);
  return 1.f - 2.f * __builtin_amdgcn_rcpf(e + 1.f);
}
// L1-bypassed (L2-served) probe; used only as the FAST probe of a monotone
// flag poll whose every-other probe is the proven agent-scope load.
DEV unsigned load_sc0(const unsigned int* p) {
  unsigned v;
  asm volatile("global_load_dword %0, %1, off sc0\n\ts_waitcnt vmcnt(0)"
               : "=v"(v) : "v"(p) : "memory");
  return v;
}
DEV unsigned load_agent(const unsigned int* p) {
  return __hip_atomic_load(p, __ATOMIC_RELAXED, __HIP_MEMORY_SCOPE_AGENT);
}
// cross-wave LDS barrier WITHOUT vmcnt drain (vae_k)
DEV void bar() {
  asm volatile("s_waitcnt lgkmcnt(0)" ::: "memory");
  __builtin_amdgcn_sched_barrier(0);
  __builtin_amdgcn_s_barrier();
  __builtin_amdgcn_sched_barrier(0);
}

// ------------------------------------------------------------------
// pack kernels
// ------------------------------------------------------------------
// cov -> MFMA A-fragment image [t(192)][g(16)][kf(2)][lane(64)][8] bf16
__global__ void pack_covf_k(const float* __restrict__ past, const float* __restrict__ fut,
                            short* __restrict__ covf) {
  const int n = 192 * 16 * 2 * 512;
  for (int i = blockIdx.x * blockDim.x + threadIdx.x; i < n; i += gridDim.x * blockDim.x) {
    int e = i & 7, l = (i >> 3) & 63, kf = (i >> 9) & 1, g = (i >> 10) & 15, t = i >> 14;
    int b = g * 16 + (l & 15);
    int col = kf * 32 + (l >> 4) * 8 + e;
    float v = (t < 128) ? past[((size_t)b * 128 + t) * 64 + col]
                        : fut[((size_t)b * 64 + (t - 128)) * 64 + col];
    covf[i] = f2bf(v);
  }
}

__global__ void pack_lab_k(const float* __restrict__ lab, short* __restrict__ labp) {
  const int n = 128 * 256 * 32;
  for (int i = blockIdx.x * blockDim.x + threadIdx.x; i < n; i += gridDim.x * blockDim.x) {
    int c = i & 31, r = i >> 5;
    int b = r & 255, t = r >> 8;
    labp[i] = f2bf(lab[((size_t)b * 128 + t) * 32 + c]);
  }
}

DEV int gru_srcrow(int pr) {
  int j = pr / 96, w = pr % 96;
  return ((w >> 5) << 9) + j * 32 + (w & 31);
}

__global__ void pack_gru_k(const float* __restrict__ Wih, const float* __restrict__ Whh,
                           const float* __restrict__ bih, const float* __restrict__ bhh,
                           int Kin, short* __restrict__ Wihp, short* __restrict__ Whhp,
                           float* __restrict__ bihp, float* __restrict__ bhhp) {
  const int nW1 = 1536 * Kin, nW2 = 1536 * 512;
  const int total = nW1 + nW2 + 3072;
  for (int idx = blockIdx.x * blockDim.x + threadIdx.x; idx < total; idx += gridDim.x * blockDim.x) {
    if (idx < nW1) {
      int pr = idx / Kin, k = idx - pr * Kin;
      Wihp[idx] = f2bf(Wih[(size_t)gru_srcrow(pr) * Kin + k]);
    } else if (idx < nW1 + nW2) {
      int ii = idx - nW1;
      int j = ii / 49152, r = ii - j * 49152;
      int i = r & 7, slot = r >> 3;
      int l = slot & 63, sf = slot >> 6;
      int kqg = sf / 6, tile = sf - kqg * 6;
      int w = tile * 16 + (l & 15);
      int k = kqg * 32 + (l >> 4) * 8 + i;
      int srow = (w >> 5) * 512 + j * 32 + (w & 31);
      Whhp[ii] = f2bf(Whh[(size_t)srow * 512 + k]);
    } else if (idx < nW1 + nW2 + 1536) {
      int pr = idx - nW1 - nW2;
      bihp[pr] = bih[gru_srcrow(pr)];
    } else {
      int pr = idx - nW1 - nW2 - 1536;
      bhhp[pr] = bhh[gru_srcrow(pr)];
    }
  }
}

// Wih0 -> B-fragment image [j(16)][tile(6)][kf(2)][lane(64)][8] bf16
__global__ void pack_wih0f_k(const float* __restrict__ Wih0, short* __restrict__ wf) {
  const int n = 16 * 6 * 2 * 512;
  for (int i = blockIdx.x * blockDim.x + threadIdx.x; i < n; i += gridDim.x * blockDim.x) {
    int j = i / 6144, r = i - j * 6144;
    int tile = r >> 10, kf = (r >> 9) & 1, l = (r >> 3) & 63, e = r & 7;
    int srow = gru_srcrow(j * 96 + tile * 16 + (l & 15));
    int k = kf * 32 + (l >> 4) * 8 + e;
    wf[i] = f2bf(Wih0[(size_t)srow * 64 + k]);
  }
}

__global__ void pack_misc_k(const float* __restrict__ fw, const float* __restrict__ w1,
                            const float* __restrict__ w2, short* __restrict__ fwb,
                            short* __restrict__ w1b, short* __restrict__ w2b) {
  const int n1 = 64 * 512, n2 = 128 * 32, n3 = 128 * 128;
  const int total = n1 + n2 + n3;
  for (int i = blockIdx.x * blockDim.x + threadIdx.x; i < total; i += gridDim.x * blockDim.x) {
    if (i < n1) fwb[i] = f2bf(fw[i]);
    else if (i < n1 + n2) w1b[i - n1] = f2bf(w1[i - n1]);
    else w2b[i - n1 - n2] = f2bf(w2[i - n1 - n2]);
  }
}

__global__ void pack_vae_k(const float* __restrict__ outW, const float* __restrict__ cmuW,
                           const float* __restrict__ W1, const float* __restrict__ W2,
                           short* __restrict__ vwf) {
  const int n = 52 * 512;
  for (int i = blockIdx.x * blockDim.x + threadIdx.x; i < n; i += gridDim.x * blockDim.x) {
    int fr = i >> 9, l = (i >> 3) & 63, e = i & 7;
    int lm = l & 15, lh = l >> 4;
    float v;
    if (fr < 4) { int kt = fr >> 1, nt = fr & 1; v = outW[(nt * 16 + lm) * 64 + kt * 32 + lh * 8 + e]; }
    else if (fr < 12) { int f = fr - 4, kt = f >> 2, nt = f & 3; v = cmuW[(nt * 16 + lm) * 64 + kt * 32 + lh * 8 + e]; }
    else if (fr < 20) { int nt = fr - 12; v = W1[(nt * 16 + lm) * 32 + lh * 8 + e]; }
    else { int f = fr - 20, kt = f >> 3, nt = f & 7; v = W2[(nt * 16 + lm) * 128 + kt * 32 + lh * 8 + e]; }
    vwf[i] = f2bf(v);
  }
}

// ------------------------------------------------------------------
// GEMM (unchanged)
// ------------------------------------------------------------------
template <int BK, bool OBF16, bool DOTANH, bool AFRAG, int CMODE = 0>
__global__ __launch_bounds__(256) void gemm_bt_k(
    const short* __restrict__ A, const short* __restrict__ Bw,
    const float* __restrict__ bias, void* __restrict__ Cout,
    int M, int N, int K) {
  constexpr int BM = 128, BN = 128;
  __shared__ short As[BM * BK];
  __shared__ short Bs[BN * BK];
  const int tid = threadIdx.x, lane = tid & 63;
  const int wave = tid >> 6, wm = wave >> 1, wn = wave & 1;
  const int bm = blockIdx.x, bn = blockIdx.y;
  const int lm = lane & 15, lk = (lane >> 4) * 8;
  f32x4 acc[4][4] = {};
  for (int k0 = 0; k0 < K; k0 += BK) {
    constexpr int BYTES = BM * BK * 2;
#pragma unroll
    for (int it = 0; it < BYTES / 4096; ++it) {
      int o = it * 4096 + tid * 16;
      if (AFRAG) {
        int sub = o >> 10, gl = sub >> 1, kk2 = sub & 1, inb = o & 1023;
        size_t region = ((size_t)(bm >> 1) * 16 + (bm & 1) * 8 + gl) * 16 + (k0 >> 5) + kk2;
        gload_lds16((const char*)A + region * 1024 + inb, (char*)As + (o - lane * 16));
      } else {
        int row = o / (BK * 2);
        int col = o - row * (BK * 2);
        const char* srcA = (const char*)A + (((size_t)(bm * BM + row)) * K + k0) * 2 + col;
        gload_lds16(srcA, (char*)As + (o - lane * 16));
      }
      int row = o / (BK * 2);
      int col = o - row * (BK * 2);
      int rb = bn * BN + row;
      if (rb >= N) rb = N - 1;
      const char* srcB = (const char*)Bw + (((size_t)rb) * K + k0) * 2 + col;
      gload_lds16(srcB, (char*)Bs + (o - lane * 16));
    }
    __syncthreads();
#pragma unroll
    for (int kk = 0; kk < BK / 32; ++kk) {
      short8 av[4], bv[4];
#pragma unroll
      for (int i = 0; i < 4; ++i) {
        if (AFRAG)
          av[i] = *(const short8*)((const char*)As + (((wm * 4 + i) * 2 + kk) << 10) + lane * 16);
        else
          av[i] = *(const short8*)((const char*)As + ((wm * 64 + i * 16 + lm) * BK + kk * 32 + lk) * 2);
      }
#pragma unroll
      for (int jv = 0; jv < 4; ++jv)
        bv[jv] = *(const short8*)((const char*)Bs + ((wn * 64 + jv * 16 + lm) * BK + kk * 32 + lk) * 2);
#pragma unroll
      for (int i = 0; i < 4; ++i)
#pragma unroll
        for (int jv = 0; jv < 4; ++jv)
          acc[i][jv] = __builtin_amdgcn_mfma_f32_16x16x32_bf16(av[i], bv[jv], acc[i][jv], 0, 0, 0);
    }
    __syncthreads();
  }
  if (CMODE == 1) {
    const int NT = N >> 4;
#pragma unroll
    for (int jv = 0; jv < 4; ++jv) {
      int col = bn * BN + wn * 64 + jv * 16 + lm;
      if (col >= N) continue;
      float bvl = bias[col];
#pragma unroll
      for (int i = 0; i < 4; ++i) {
        int rowblk = bm * 8 + wm * 4 + i;
        f32x4 v = acc[i][jv];
        v[0] += bvl; v[1] += bvl; v[2] += bvl; v[3] += bvl;
        *(f32x4*)((float*)Cout + (((size_t)rowblk * NT + (col >> 4)) << 8) + lane * 4) = v;
      }
    }
  } else {
#pragma unroll
    for (int jv = 0; jv < 4; ++jv) {
      int col = bn * BN + wn * 64 + jv * 16 + lm;
      if (col >= N) continue;
      float bvl = bias[col];
#pragma unroll
      for (int i = 0; i < 4; ++i) {
        int row0 = bm * BM + wm * 64 + i * 16 + (lane >> 4) * 4;
#pragma unroll
        for (int r = 0; r < 4; ++r) {
          float v = acc[i][jv][r] + bvl;
          if (DOTANH) v = tanhf(v);
          size_t off = (size_t)(row0 + r) * N + col;
          if (OBF16) ((short*)Cout)[off] = f2bf(v);
          else ((float*)Cout)[off] = v;
        }
      }
    }
  }
}

// ------------------------------------------------------------------
// GRU scan: R7 agent-scope protocol (proven), poll = alternating sc0/agent
// probes of a MONOTONE flag (worst case == R7; best case L2-latency poll).
// XGF=1: layer-0 xg fused in-kernel via 3 extra MFMAs/wave.
//   r,z gates: cov-part accumulated directly into a3 (sums add in gates).
//   n gate: cov-part kept SEPARATE (ax0/ax1 -> scx) since n = tanh(xn + r*hn).
// ------------------------------------------------------------------
template <int SCHEME, int XGF>
__global__ __launch_bounds__(256) void gru_scan_k(
    const short* __restrict__ xg,      // XGF=0: [48*256*1536] bf16
    const short* __restrict__ covf,    // XGF=1: cov A-frag image
    const short* __restrict__ wihf_g,  // XGF=1: Wih0 B-frag image
    const short* __restrict__ Whhp,
    const float* __restrict__ bihp,    // XGF=1 only
    const float* __restrict__ bhhp,
    short* __restrict__ hbuf,
    unsigned int* __restrict__ ctr,
    unsigned int* __restrict__ flags,
    int t0, int nsteps) {
  __shared__ short Wl[96 * 512];
  __shared__ short hs[16 * 512];
  __shared__ float sc[2][16 * 101];
  __shared__ float scx[2][16 * 33];
  __shared__ float bhs[96];
  __shared__ float bihn[32];
  const int tid = threadIdx.x, lane = tid & 63, wave = tid >> 6;
  const int x = blockIdx.x;
  const int g = (x & 7) + ((x >> 7) << 3);
  const int j = (x >> 3) & 15;
  unsigned int* __restrict__ myctr = ctr + g * 64;
  unsigned int* __restrict__ myflags = flags + g * 16;
  unsigned int* __restrict__ hbuf32 = (unsigned int*)hbuf;
  {
    const char* wsrc = (const char*)Whhp + (size_t)j * 98304;
#pragma unroll 4
    for (int it = 0; it < 24; ++it) {
      int o = it * 4096 + tid * 16;
      gload_lds16(wsrc + o, (char*)Wl + (o - lane * 16));
    }
    if (tid < 96) {
      float b = bhhp[j * 96 + tid];
      if (XGF && tid < 64) b += bihp[j * 96 + tid];
      bhs[tid] = b;
    }
    if (XGF && tid < 32) bihn[tid] = bihp[j * 96 + 64 + tid];
  }
  const int wk = wave >> 1, wn3 = wave & 1;
  const int m = tid >> 4, up = tid & 15, u0 = up * 2;
  short8 wihf0{}, wihf1{}, wihf2{};
  if (XGF) {
    wihf0 = *(const short8*)(wihf_g + ((size_t)(j * 6 + wn3 * 3 + 0) * 2 + wk) * 512 + lane * 8);
    wihf1 = *(const short8*)(wihf_g + ((size_t)(j * 6 + wn3 * 3 + 1) * 2 + wk) * 512 + lane * 8);
    wihf2 = *(const short8*)(wihf_g + ((size_t)(j * 6 + wn3 * 3 + 2) * 2 + wk) * 512 + lane * 8);
  }
  for (int tl = 0; tl < nsteps; ++tl) {
    const int t = t0 + tl;
    const char* hsrc = (const char*)hbuf + ((size_t)t * 16 + g) * 16384;
#pragma unroll
    for (int it = 0; it < 4; ++it) {
      int o = it * 4096 + tid * 16;
      gload_lds16(hsrc + o, (char*)hs + (o - lane * 16));
    }
    short8 cf{};
    unsigned int xr2 = 0, xz2 = 0, xn2 = 0;
    if (XGF) {
      cf = *(const short8*)(covf + (((size_t)t * 16 + g) * 2 + wk) * 512 + lane * 8);
    } else {
      const unsigned int* xp = (const unsigned int*)(xg + ((size_t)tl * 256 + g * 16 + m) * 1536 + j * 96);
      xr2 = xp[up]; xz2 = xp[16 + up]; xn2 = xp[32 + up];
    }
    __syncthreads();
    f32x4 a3[3] = {};
    f32x4 ax0 = {0.f, 0.f, 0.f, 0.f}, ax1 = {0.f, 0.f, 0.f, 0.f};
#pragma unroll
    for (int kq = 0; kq < 8; ++kq) {
      int kqg = wk * 8 + kq;
      short8 av = *(const short8*)((const char*)hs + (kqg << 10) + lane * 16);
#pragma unroll
      for (int n = 0; n < 3; ++n) {
        short8 bv = *(const short8*)((const char*)Wl + ((kqg * 6 + wn3 * 3 + n) << 10) + lane * 16);
        a3[n] = __builtin_amdgcn_mfma_f32_16x16x32_bf16(av, bv, a3[n], 0, 0, 0);
      }
    }
    if (XGF) {
      // tiles: wn3=0 -> {r0,r1,z0} all fused; wn3=1 -> {z1 fused, n0, n1 separate}
      a3[0] = __builtin_amdgcn_mfma_f32_16x16x32_bf16(cf, wihf0, a3[0], 0, 0, 0);
      if (wn3 == 0) {
        a3[1] = __builtin_amdgcn_mfma_f32_16x16x32_bf16(cf, wihf1, a3[1], 0, 0, 0);
        a3[2] = __builtin_amdgcn_mfma_f32_16x16x32_bf16(cf, wihf2, a3[2], 0, 0, 0);
      } else {
        ax0 = __builtin_amdgcn_mfma_f32_16x16x32_bf16(cf, wihf1, ax0, 0, 0, 0);
        ax1 = __builtin_amdgcn_mfma_f32_16x16x32_bf16(cf, wihf2, ax1, 0, 0, 0);
      }
    }
#pragma unroll
    for (int n = 0; n < 3; ++n)
#pragma unroll
      for (int rr = 0; rr < 4; ++rr)
        sc[wk][((lane >> 4) * 4 + rr) * 101 + (wn3 * 3 + n) * 16 + (lane & 15)] = a3[n][rr];
    if (XGF && wn3 == 1) {
#pragma unroll
      for (int rr = 0; rr < 4; ++rr) {
        scx[wk][((lane >> 4) * 4 + rr) * 33 + (lane & 15)] = ax0[rr];
        scx[wk][((lane >> 4) * 4 + rr) * 33 + 16 + (lane & 15)] = ax1[rr];
      }
    }
    __syncthreads();
    {
      float Sr0 = sc[0][m * 101 + u0] + sc[1][m * 101 + u0];
      float Sr1 = sc[0][m * 101 + u0 + 1] + sc[1][m * 101 + u0 + 1];
      float Sz0 = sc[0][m * 101 + 32 + u0] + sc[1][m * 101 + 32 + u0];
      float Sz1 = sc[0][m * 101 + 33 + u0] + sc[1][m * 101 + 33 + u0];
      float Sn0 = sc[0][m * 101 + 64 + u0] + sc[1][m * 101 + 64 + u0];
      float Sn1 = sc[0][m * 101 + 65 + u0] + sc[1][m * 101 + 65 + u0];
      int hpa = ((j * 64 + (up >> 2) * 16 + m) << 4) + ((u0 & 7) << 1);
      unsigned int hpu = *(const unsigned int*)((const char*)hs + hpa);
      float hp0 = bf2f((short)(hpu & 0xffff)), hp1 = bf2f((short)(hpu >> 16));
      float r0, r1, z0, z1, n0, n1;
      if (XGF) {
        float Sx0 = scx[0][m * 33 + u0] + scx[1][m * 33 + u0];
        float Sx1 = scx[0][m * 33 + u0 + 1] + scx[1][m * 33 + u0 + 1];
        r0 = sigm(Sr0 + bhs[u0]);
        r1 = sigm(Sr1 + bhs[u0 + 1]);
        z0 = sigm(Sz0 + bhs[32 + u0]);
        z1 = sigm(Sz1 + bhs[33 + u0]);
        n0 = tanhf(Sx0 + bihn[u0] + r0 * (Sn0 + bhs[64 + u0]));
        n1 = tanhf(Sx1 + bihn[u0 + 1] + r1 * (Sn1 + bhs[65 + u0]));
      } else {
        r0 = sigm(bf2f((short)(xr2 & 0xffff)) + Sr0 + bhs[u0]);
        r1 = sigm(bf2f((short)(xr2 >> 16)) + Sr1 + bhs[u0 + 1]);
        z0 = sigm(bf2f((short)(xz2 & 0xffff)) + Sz0 + bhs[32 + u0]);
        z1 = sigm(bf2f((short)(xz2 >> 16)) + Sz1 + bhs[33 + u0]);
        n0 = tanhf(bf2f((short)(xn2 & 0xffff)) + r0 * (Sn0 + bhs[64 + u0]));
        n1 = tanhf(bf2f((short)(xn2 >> 16)) + r1 * (Sn1 + bhs[65 + u0]));
      }
      float h0 = (1.f - z0) * n0 + z0 * hp0;
      float h1 = (1.f - z1) * n1 + z1 * hp1;
      unsigned int hv = (unsigned int)(unsigned short)f2bf(h0) |
                        ((unsigned int)(unsigned short)f2bf(h1) << 16);
      size_t oi = ((size_t)(t + 1) * 16 + g) * 4096 +
                  (j * 64 + (up >> 2) * 16 + m) * 4 + (up & 3);
      __hip_atomic_store(hbuf32 + oi, hv, __ATOMIC_RELAXED, __HIP_MEMORY_SCOPE_AGENT);
    }
    __syncthreads();  // drains vmcnt -> h stores acked at coherence point
    if constexpr (SCHEME == 1) {
      if (tid == 0) {
        __hip_atomic_fetch_add(myctr, 1u, __ATOMIC_RELAXED, __HIP_MEMORY_SCOPE_AGENT);
        const unsigned tgt = 16u * (unsigned)(tl + 1);
        int guard = 0;
        for (;;) {
          if (load_sc0(myctr) >= tgt) break;
          if (load_agent(myctr) >= tgt) break;
          if (++guard >= 200000) break;
        }
      }
    } else {
      const unsigned tgt = (unsigned)(tl + 1);
      if (tid == 0)
        __hip_atomic_store(myflags + j, tgt, __ATOMIC_RELAXED, __HIP_MEMORY_SCOPE_AGENT);
      if (tid < 16) {
        int guard = 0;
        for (;;) {
          if (load_sc0(myflags + tid) >= tgt) break;
          if (load_agent(myflags + tid) >= tgt) break;
          if (++guard >= 200000) break;
        }
      }
    }
    __syncthreads();
  }
}

// ------------------------------------------------------------------
// VAE scan v4 (unchanged from R7, passing at 172 us)
// ------------------------------------------------------------------
#define PAST_STEP(T, FN, CMR, CSR)                                           \
  do {                                                                       \
    f32x4 muPr, varPr;                                                       \
    _Pragma("unroll") for (int r = 0; r < 4; ++r) {                          \
      float m_ = muC[r];                                                     \
      float a_ = tanh_f(fw1 * m_ + fb1);                                     \
      muPr[r] = fu1 * a_ + FN[r] + m_;                                       \
      float cf_ = fu1 * fw1 * (1.f - a_ * a_);                               \
      varPr[r] = 2.f * cf_ * varC[r] + varC[r] + 1.f;                        \
    }                                                                        \
    f32x4 cmNow = CMR, csNow = CSR;                                          \
    FN = *(const f32x4*)(feat_img + (((size_t)((T) + 2) * 16 + bg) * 4 + w) * 256 + l * 4); \
    if ((T) + 2 < 128) {                                                     \
      CMR = *(const f32x4*)(ctrl_img + (((size_t)((T) + 2) * 16 + bg) * 8 + w) * 256 + l * 4); \
      CSR = *(const f32x4*)(ctrl_img + (((size_t)((T) + 2) * 16 + bg) * 8 + 4 + w) * 256 + l * 4); \
    }                                                                        \
    _Pragma("unroll") for (int r = 0; r < 4; ++r) {                          \
      int row_ = m4 * 4 + r;                                                 \
      *(short*)((char*)muA + ((row_ * 128 + (w * 16 + c) * 2) ^ ((row_ & 7) << 4))) = f2bf(muPr[r]); \
    }                                                                        \
    bar();                                                                   \
    short8 muAf0 = *(const short8*)((const char*)muA + ((c * 128 + m4 * 16) ^ ((c & 7) << 4))); \
    short8 muAf1 = *(const short8*)((const char*)muA + ((c * 128 + 64 + m4 * 16) ^ ((c & 7) << 4))); \
    if (w == 0) *(short8*)(muprb + (((size_t)(T) * 16 + bg) * 2) * 512 + l * 8) = muAf0; \
    if (w == 1) *(short8*)(muprb + (((size_t)(T) * 16 + bg) * 2 + 1) * 512 + l * 8) = muAf1; \
    f32x4 mcC = {0.f, 0.f, 0.f, 0.f};                                        \
    mcC = __builtin_amdgcn_mfma_f32_16x16x32_bf16(muAf0, cmuf0, mcC, 0, 0, 0); \
    mcC = __builtin_amdgcn_mfma_f32_16x16x32_bf16(muAf1, cmuf1, mcC, 0, 0, 0); \
    bar();                                                                   \
    _Pragma("unroll") for (int r = 0; r < 4; ++r) {                          \
      float vp_ = varPr[r], mp_ = muPr[r];                                   \
      float cmv_ = cmNow[r] - (mcC[r] + cmub1);                              \
      float x_ = csNow[r];                                                   \
      float cs_ = (x_ > 20.f) ? x_ : __logf(1.f + __expf(x_));               \
      if ((T) >= 1) {                                                        \
        size_t b_ = (size_t)(bg * 16 + m4 * 4 + r);                          \
        out[1572864 + b_ * 12224 + (size_t)((T) - 1) * 64 + w * 16 + c] = cmv_; \
        out[4702208 + b_ * 12224 + (size_t)((T) - 1) * 64 + w * 16 + c] = cs_;  \
      }                                                                      \
      float s_ = cs_ + vp_;                                                  \
      float rs_ = __builtin_amdgcn_rcpf(s_);                                 \
      muC[r] = cs_ * rs_ * mp_ + vp_ * rs_ * cmv_;                           \
      varC[r] = vp_ * cs_ * rs_;                                             \
    }                                                                        \
  } while (0)

#define FUT_STEP(T, FN)                                                      \
  do {                                                                       \
    f32x4 muPr, varPr;                                                       \
    _Pragma("unroll") for (int r = 0; r < 4; ++r) {                          \
      float m_ = muC[r];                                                     \
      float a_ = tanh_f(fw1 * m_ + fb1);                                     \
      muPr[r] = fu1 * a_ + FN[r] + m_;                                       \
      float cf_ = fu1 * fw1 * (1.f - a_ * a_);                               \
      varPr[r] = 2.f * cf_ * varC[r] + varC[r] + 1.f;                        \
    }                                                                        \
    if ((T) + 2 < 192)                                                       \
      FN = *(const f32x4*)(feat_img + (((size_t)((T) + 2) * 16 + bg) * 4 + w) * 256 + l * 4); \
    _Pragma("unroll") for (int r = 0; r < 4; ++r) {                          \
      int row_ = m4 * 4 + r;                                                 \
      *(short*)((char*)muA + ((row_ * 128 + (w * 16 + c) * 2) ^ ((row_ & 7) << 4))) = f2bf(muPr[r]); \
    }                                                                        \
    bar();                                                                   \
    short8 muAf0 = *(const short8*)((const char*)muA + ((c * 128 + m4 * 16) ^ ((c & 7) << 4))); \
    short8 muAf1 = *(const short8*)((const char*)muA + ((c * 128 + 64 + m4 * 16) ^ ((c & 7) << 4))); \
    f32x4 mcC = {0.f, 0.f, 0.f, 0.f};                                        \
    mcC = __builtin_amdgcn_mfma_f32_16x16x32_bf16(muAf0, cmuf0, mcC, 0, 0, 0); \
    mcC = __builtin_amdgcn_mfma_f32_16x16x32_bf16(muAf1, cmuf1, mcC, 0, 0, 0); \
    if (w < 2) {                                                             \
      f32x4 predC = {0.f, 0.f, 0.f, 0.f};                                    \
      predC = __builtin_amdgcn_mfma_f32_16x16x32_bf16(muAf0, outWf0, predC, 0, 0, 0); \
      predC = __builtin_amdgcn_mfma_f32_16x16x32_bf16(muAf1, outWf1, predC, 0, 0, 0); \
      _Pragma("unroll") for (int r = 0; r < 4; ++r) {                        \
        float pv_ = predC[r] + outb1;                                        \
        out[(size_t)(bg * 16 + m4 * 4 + r) * 6144 + (T) * 32 + w * 16 + c] = pv_; \
        int row_ = m4 * 4 + r;                                               \
        *(short*)((char*)predA + ((row_ * 64 + (w * 16 + c) * 2) ^ ((row_ & 3) << 4))) = f2bf(pv_); \
      }                                                                      \
    }                                                                        \
    bar();                                                                   \
    short8 pAf = *(const short8*)((const char*)predA + ((c * 64 + m4 * 16) ^ ((c & 3) << 4))); \
    f32x4 z0 = {0.f, 0.f, 0.f, 0.f}, z1 = {0.f, 0.f, 0.f, 0.f};              \
    z0 = __builtin_amdgcn_mfma_f32_16x16x32_bf16(pAf, *(const short8*)((const char*)Wctl + (2 * w) * 1024 + l * 16), z0, 0, 0, 0); \
    z1 = __builtin_amdgcn_mfma_f32_16x16x32_bf16(pAf, *(const short8*)((const char*)Wctl + (2 * w + 1) * 1024 + l * 16), z1, 0, 0, 0); \
    _Pragma("unroll") for (int r = 0; r < 4; ++r) {                          \
      int row_ = m4 * 4 + r;                                                 \
      *(short*)((char*)hdnA + ((row_ * 256 + ((2 * w) * 16 + c) * 2) ^ ((row_ & 7) << 4))) = f2bf(tanh_f(z0[r] + b1a)); \
      *(short*)((char*)hdnA + ((row_ * 256 + ((2 * w + 1) * 16 + c) * 2) ^ ((row_ & 7) << 4))) = f2bf(tanh_f(z1[r] + b1b)); \
    }                                                                        \
    bar();                                                                   \
    short8 hAf0 = *(const short8*)((const char*)hdnA + ((c * 256 + 0 * 64 + m4 * 16) ^ ((c & 7) << 4))); \
    short8 hAf1 = *(const short8*)((const char*)hdnA + ((c * 256 + 1 * 64 + m4 * 16) ^ ((c & 7) << 4))); \
    short8 hAf2 = *(const short8*)((const char*)hdnA + ((c * 256 + 2 * 64 + m4 * 16) ^ ((c & 7) << 4))); \
    short8 hAf3 = *(const short8*)((const char*)hdnA + ((c * 256 + 3 * 64 + m4 * 16) ^ ((c & 7) << 4))); \
    f32x4 zcm = {0.f, 0.f, 0.f, 0.f}, zcs = {0.f, 0.f, 0.f, 0.f};            \
    zcm = __builtin_amdgcn_mfma_f32_16x16x32_bf16(hAf0, *(const short8*)((const char*)Wctl + (8 + 0 * 8 + w) * 1024 + l * 16), zcm, 0, 0, 0); \
    zcm = __builtin_amdgcn_mfma_f32_16x16x32_bf16(hAf1, *(const short8*)((const char*)Wctl + (8 + 1 * 8 + w) * 1024 + l * 16), zcm, 0, 0, 0); \
    zcm = __builtin_amdgcn_mfma_f32_16x16x32_bf16(hAf2, *(const short8*)((const char*)Wctl + (8 + 2 * 8 + w) * 1024 + l * 16), zcm, 0, 0, 0); \
    zcm = __builtin_amdgcn_mfma_f32_16x16x32_bf16(hAf3, *(const short8*)((const char*)Wctl + (8 + 3 * 8 + w) * 1024 + l * 16), zcm, 0, 0, 0); \
    zcs = __builtin_amdgcn_mfma_f32_16x16x32_bf16(hAf0, *(const short8*)((const char*)Wctl + (8 + 0 * 8 + 4 + w) * 1024 + l * 16), zcs, 0, 0, 0); \
    zcs = __builtin_amdgcn_mfma_f32_16x16x32_bf16(hAf1, *(const short8*)((const char*)Wctl + (8 + 1 * 8 + 4 + w) * 1024 + l * 16), zcs, 0, 0, 0); \
    zcs = __builtin_amdgcn_mfma_f32_16x16x32_bf16(hAf2, *(const short8*)((const char*)Wctl + (8 + 2 * 8 + 4 + w) * 1024 + l * 16), zcs, 0, 0, 0); \
    zcs = __builtin_amdgcn_mfma_f32_16x16x32_bf16(hAf3, *(const short8*)((const char*)Wctl + (8 + 3 * 8 + 4 + w) * 1024 + l * 16), zcs, 0, 0, 0); \
    bar();                                                                   \
    _Pragma("unroll") for (int r = 0; r < 4; ++r) {                          \
      float vp_ = varPr[r], mp_ = muPr[r];                                   \
      float cmv_ = (zcm[r] + b2cm) - (mcC[r] + cmub1);                       \
      float x_ = zcs[r] + b2cs;                                              \
      float cs_ = (x_ > 20.f) ? x_ : __logf(1.f + __expf(x_));               \
      size_t b_ = (size_t)(bg * 16 + m4 * 4 + r);                            \
      out[1572864 + b_ * 12224 + (size_t)((T) - 1) * 64 + w * 16 + c] = cmv_; \
      out[4702208 + b_ * 12224 + (size_t)((T) - 1) * 64 + w * 16 + c] = cs_;  \
      float s_ = cs_ + vp_;                                                  \
      float rs_ = __builtin_amdgcn_rcpf(s_);                                 \
      muC[r] = cs_ * rs_ * mp_ + vp_ * rs_ * cmv_;                           \
      varC[r] = vp_ * cs_ * rs_;                                             \
    }                                                                        \
  } while (0)

__global__ __launch_bounds__(256) void vae_k(
    const float* __restrict__ feat_img, const float* __restrict__ ctrl_img,
    const short* __restrict__ vwf,
    const float* __restrict__ flow_u, const float* __restrict__ flow_w,
    const float* __restrict__ flow_b, const float* __restrict__ outb,
    const float* __restrict__ b1, const float* __restrict__ b2,
    const float* __restrict__ cmub, short* __restrict__ muprb,
    float* __restrict__ out) {
  __shared__ short Wctl[40 * 512];
  __shared__ short muA[16 * 64];
  __shared__ short predA[16 * 32];
  __shared__ short hdnA[16 * 128];
  const int tid = threadIdx.x, l = tid & 63, w = tid >> 6;
  const int m4 = l >> 4, c = l & 15, bg = blockIdx.x;
  {
    const char* src = (const char*)vwf + 12288;
#pragma unroll
    for (int it = 0; it < 10; ++it) {
      int o = it * 4096 + tid * 16;
      gload_lds16(src + o, (char*)Wctl + (o - l * 16));
    }
  }
  short8 cmuf0 = *(const short8*)(vwf + (4 + w) * 512 + l * 8);
  short8 cmuf1 = *(const short8*)(vwf + (8 + w) * 512 + l * 8);
  short8 outWf0 = *(const short8*)(vwf + ((w & 1)) * 512 + l * 8);
  short8 outWf1 = *(const short8*)(vwf + (2 + (w & 1)) * 512 + l * 8);
  float fw1 = flow_w[w * 16 + c], fu1 = flow_u[w * 16 + c];
  float fb1 = flow_b[w * 16 + c], cmub1 = cmub[w * 16 + c];
  float outb1 = outb[(w & 1) * 16 + c];
  float b1a = b1[(2 * w) * 16 + c], b1b = b1[(2 * w + 1) * 16 + c];
  float b2cm = b2[w * 16 + c], b2cs = b2[(4 + w) * 16 + c];
  f32x4 muC = {0.f, 0.f, 0.f, 0.f}, varC = {1.f, 1.f, 1.f, 1.f};
  f32x4 fN0 = *(const f32x4*)(feat_img + ((size_t)bg * 4 + w) * 256 + l * 4);
  f32x4 fN1 = *(const f32x4*)(feat_img + ((size_t)(16 + bg) * 4 + w) * 256 + l * 4);
  f32x4 cmA = *(const f32x4*)(ctrl_img + ((size_t)bg * 8 + w) * 256 + l * 4);
  f32x4 csA = *(const f32x4*)(ctrl_img + ((size_t)bg * 8 + 4 + w) * 256 + l * 4);
  f32x4 cmB = *(const f32x4*)(ctrl_img + ((size_t)(16 + bg) * 8 + w) * 256 + l * 4);
  f32x4 csB = *(const f32x4*)(ctrl_img + ((size_t)(16 + bg) * 8 + 4 + w) * 256 + l * 4);
  __syncthreads();
  for (int t2 = 0; t2 < 128; t2 += 2) {
    PAST_STEP(t2, fN0, cmA, csA);
    PAST_STEP(t2 + 1, fN1, cmB, csB);
  }
  asm volatile("s_waitcnt vmcnt(0)" ::: "memory");
  __builtin_amdgcn_sched_barrier(0);
  __builtin_amdgcn_s_barrier();
  for (int t2 = 128; t2 < 192; t2 += 2) {
    FUT_STEP(t2, fN0);
    FUT_STEP(t2 + 1, fN1);
  }
}

// ------------------------------------------------------------------
// pred_past_k (unchanged)
// ------------------------------------------------------------------
__global__ __launch_bounds__(512) void pred_past_k(
    const short* __restrict__ muprb, const short* __restrict__ vwf,
    const float* __restrict__ outb, float* __restrict__ out) {
  const int l = threadIdx.x & 63;
  const int w = blockIdx.x * 8 + (threadIdx.x >> 6);
  const int t = w >> 4, bg = w & 15;
  const int m4 = l >> 4, c = l & 15;
  short8 a0 = *(const short8*)(muprb + ((size_t)w * 2 + 0) * 512 + l * 8);
  short8 a1 = *(const short8*)(muprb + ((size_t)w * 2 + 1) * 512 + l * 8);
  float outb2[2] = {outb[c], outb[16 + c]};
#pragma unroll
  for (int nt = 0; nt < 2; ++nt) {
    short8 w0 = *(const short8*)(vwf + (0 * 2 + nt) * 512 + l * 8);
    short8 w1 = *(const short8*)(vwf + (1 * 2 + nt) * 512 + l * 8);
    f32x4 p = {0.f, 0.f, 0.f, 0.f};
    p = __builtin_amdgcn_mfma_f32_16x16x32_bf16(a0, w0, p, 0, 0, 0);
    p = __builtin_amdgcn_mfma_f32_16x16x32_bf16(a1, w1, p, 0, 0, 0);
#pragma unroll
    for (int r = 0; r < 4; ++r)
      out[(size_t)(bg * 16 + m4 * 4 + r) * 6144 + t * 32 + nt * 16 + c] = p[r] + outb2[nt];
  }
}

// ------------------------------------------------------------------
extern "C" void kernel_launch(void* const* d_in, const int* in_sizes, int n_in,
                              void* d_out, int out_size, void* d_ws, size_t ws_size,
                              hipStream_t stream) {
  (void)in_sizes; (void)n_in; (void)out_size; (void)ws_size;
  const float* past_input = (const float*)d_in[0];
  const float* past_label = (const float*)d_in[1];
  const float* future_input = (const float*)d_in[2];
  const float* Wih0 = (const float*)d_in[3];
  const float* Whh0 = (const float*)d_in[4];
  const float* bih0 = (const float*)d_in[5];
  const float* bhh0 = (const float*)d_in[6];
  const float* Wih1 = (const float*)d_in[7];
  const float* Whh1 = (const float*)d_in[8];
  const float* bih1 = (const float*)d_in[9];
  const float* bhh1 = (const float*)d_in[10];
  const float* flow_u = (const float*)d_in[11];
  const float* flow_w = (const float*)d_in[12];
  const float* flow_b = (const float*)d_in[13];
  const float* feat_W = (const float*)d_in[14];
  const float* feat_b = (const float*)d_in[15];
  const float* ctrl_W1 = (const float*)d_in[16];
  const float* ctrl_b1 = (const float*)d_in[17];
  const float* ctrl_W2 = (const float*)d_in[18];
  const float* ctrl_b2 = (const float*)d_in[19];
  const float* cmuW = (const float*)d_in[20];
  const float* cmub = (const float*)d_in[21];
  const float* outW = (const float*)d_in[22];
  const float* outb = (const float*)d_in[23];

  char* ws = (char*)d_ws;
  size_t off = 0;
  auto alloc = [&](size_t bytes) -> char* {
    char* p = ws + off;
    off += (bytes + 255) & ~(size_t)255;
    return p;
  };
  short* covf  = (short*)alloc(192ull * 16 * 2 * 512 * 2);   // cov A-frag image
  short* labp  = (short*)alloc(32768ull * 32 * 2);
  short* Wih0p = (short*)alloc(1536ull * 64 * 2);            // unused (pack_gru still fills)
  short* Whh0p = (short*)alloc(1536ull * 512 * 2);
  short* Wih1p = (short*)alloc(1536ull * 512 * 2);
  short* Whh1p = (short*)alloc(1536ull * 512 * 2);
  float* bih0p = (float*)alloc(1536 * 4);
  float* bhh0p = (float*)alloc(1536 * 4);
  float* bih1p = (float*)alloc(1536 * 4);
  float* bhh1p = (float*)alloc(1536 * 4);
  short* featWb = (short*)alloc(64ull * 512 * 2);
  short* W1b   = (short*)alloc(128ull * 32 * 2);
  short* W2b   = (short*)alloc(128ull * 128 * 2);
  short* vwf   = (short*)alloc(52ull * 512 * 2);
  short* wih0f = (short*)alloc(16ull * 6 * 2 * 512 * 2);     // Wih0 B-frag image
  short* xgc   = (short*)alloc(48ull * 256 * 1536 * 2);      // L1 xg chunks only
  short* h1buf = (short*)alloc(193ull * 256 * 512 * 2);
  short* cfbuf = (short*)alloc(193ull * 256 * 512 * 2);
  unsigned int* ctr = (unsigned int*)alloc(8 * 16 * 64 * 4);
  unsigned int* flg = (unsigned int*)alloc(8 * 16 * 16 * 4);
  float* feat_img = (float*)xgc;                             // overlays after scans
  short* hdnb     = (short*)((char*)xgc + 12582912);
  float* ctrl_img = (float*)((char*)xgc + 20971520);
  short* muprb    = (short*)covf;  // covf dead after L0 scan; vae writes after scans

  hipMemsetAsync(ctr, 0, 8 * 16 * 64 * 4, stream);
  hipMemsetAsync(flg, 0, 8 * 16 * 16 * 4, stream);
  hipMemsetAsync(h1buf, 0, 256 * 512 * 2, stream);
  hipMemsetAsync(cfbuf, 0, 256 * 512 * 2, stream);

  pack_covf_k<<<2048, 256, 0, stream>>>(past_input, future_input, covf);
  pack_lab_k<<<1024, 256, 0, stream>>>(past_label, labp);
  pack_gru_k<<<1024, 256, 0, stream>>>(Wih0, Whh0, bih0, bhh0, 64, Wih0p, Whh0p, bih0p, bhh0p);
  pack_gru_k<<<1024, 256, 0, stream>>>(Wih1, Whh1, bih1, bhh1, 512, Wih1p, Whh1p, bih1p, bhh1p);
  pack_wih0f_k<<<96, 256, 0, stream>>>(Wih0, wih0f);
  pack_misc_k<<<64, 256, 0, stream>>>(feat_W, ctrl_W1, ctrl_W2, featWb, W1b, W2b);
  pack_vae_k<<<104, 256, 0, stream>>>(outW, cmuW, ctrl_W1, ctrl_W2, vwf);

  // layer 0: single 192-step scan, xg fused in-kernel (no L0 GEMMs)
  gru_scan_k<2, 1><<<256, 256, 0, stream>>>(
      nullptr, covf, wih0f, Whh0p, bih0p, bhh0p, h1buf,
      ctr, flg, 0, 192);
  // layer 1: 4 chunks (xg GEMM + 48-step scan), scheme A/B as before
  for (int c = 0; c < 4; ++c) {
    gemm_bt_k<64, true, false, true><<<dim3(96, 12), 256, 0, stream>>>(
        h1buf + (size_t)(1 + c * 48) * 131072, Wih1p, bih1p, xgc, 12288, 1536, 512);
    int d = 4 + c;
    if (c & 1)
      gru_scan_k<2, 0><<<256, 256, 0, stream>>>(
          xgc, nullptr, nullptr, Whh1p, nullptr, bhh1p, cfbuf,
          ctr + d * 1024, flg + d * 256, c * 48, 48);
    else
      gru_scan_k<1, 0><<<256, 256, 0, stream>>>(
          xgc, nullptr, nullptr, Whh1p, nullptr, bhh1p, cfbuf,
          ctr + d * 1024, flg + d * 256, c * 48, 48);
  }
  gemm_bt_k<64, false, false, true, 1><<<dim3(384, 1), 256, 0, stream>>>(
      cfbuf + 131072, featWb, feat_b, feat_img, 49152, 64, 512);
  gemm_bt_k<32, true, true, false><<<dim3(256, 1), 256, 0, stream>>>(
      labp, W1b, ctrl_b1, hdnb, 32768, 128, 32);
  gemm_bt_k<64, false, false, false, 1><<<dim3(256, 1), 256, 0, stream>>>(
      hdnb, W2b, ctrl_b2, ctrl_img, 32768, 128, 128);

  vae_k<<<16, 256, 0, stream>>>(feat_img, ctrl_img, vwf, flow_u, flow_w, flow_b,
                                outb, ctrl_b1, ctrl_b2, cmub, muprb, (float*)d_out);
  pred_past_k<<<256, 512, 0, stream>>>(muprb, vwf, outb, (float*)d_out);
}